// Round 6
// baseline (209.929 us; speedup 1.0000x reference)
//
#include <hip/hip_runtime.h>

#define CH 16
#define NB 8
// bpre layout (u16 elements):
//   [0 .. 4*7168)        : legacy stage 0..3 B-fragments (tail uses s=3)
//   [4*7168 .. +3584)    : stem weight A-fragments [i=0..6][lane][j]
//   [WOFF .. +3*7168)    : stage 0..2 A-weight fragments, K = tap*8+cin,
//                          [s][h=cin-half][i=0..6][lane][j]
#define WOFF (4 * 7168 + 3584)
#define WPRE_TOT (WOFF + 3 * 7168)

typedef unsigned short u16;
typedef unsigned char u8;
typedef unsigned int u32;
typedef __attribute__((ext_vector_type(8))) short s16x8;
typedef __attribute__((ext_vector_type(4))) float f32x4;

__device__ __forceinline__ float bflo(u32 u) { return __uint_as_float(u << 16); }
__device__ __forceinline__ float bfhi(u32 u) { return __uint_as_float(u & 0xffff0000u); }
__device__ __forceinline__ u32 bfrnd(float f) {
  u32 u = __float_as_uint(f);
  return (u + 0x7fffu + ((u >> 16) & 1u)) >> 16;
}
__device__ __forceinline__ u32 packbf_hw(float lo, float hi) {
  u32 r;
  asm("v_cvt_pk_bf16_f32 %0, %1, %2" : "=v"(r) : "v"(lo), "v"(hi));
  return r;
}

// ---- Prep: all weight fragments (once) ------------------------------------
__global__ __launch_bounds__(256) void bprep_kernel(
    const float* __restrict__ w_stg, const float* __restrict__ w_stem,
    u16* __restrict__ bpre)
{
  const int e = blockIdx.x * 256 + (int)threadIdx.x;
  if (e >= WPRE_TOT) return;
  if (e < 4 * 7168) {
    const int s = e / 7168, r0 = e % 7168;
    const int i = r0 >> 9;
    const int r = r0 & 511;
    const int l = r >> 3, j = r & 7;
    const int tap = 2 * i + (l >> 5);
    const int cin = ((l >> 4) & 1) * 8 + j;
    const int n = l & 15;
    const float* w = w_stg + s * 27 * 256;
    const float val = (tap < 27) ? w[(tap * 16 + cin) * 16 + n] : 0.f;
    bpre[s * 7168 + i * 512 + l * 8 + j] = (u16)bfrnd(val);
  } else if (e < WOFF) {
    const int e2 = e - 4 * 7168;          // stem: [i][lane][j]
    const int i = e2 >> 9;
    const int r0 = e2 & 511;
    const int lane = r0 >> 3, j = r0 & 7;
    const int quad = lane >> 4, n = lane & 15;
    const int r = i * 4 + quad;
    const float val = (r < 25 && j < 5) ? w_stem[(r * 5 + j) * 16 + n] : 0.f;
    bpre[4 * 7168 + e2] = (u16)bfrnd(val);
  } else {
    // stage A-weights: k = tap*8 + cin (cin-half h); lane = quad*16+n
    const int e3 = e - WOFF;
    const int s = e3 / 7168;
    const int r = e3 % 7168;
    const int h = r / 3584;
    const int r2 = r % 3584;
    const int i = r2 >> 9;
    const int l = (r2 >> 3) & 63;
    const int j = r2 & 7;
    const int quad = l >> 4, n = l & 15;
    const int tap = i * 4 + quad;
    const float val =
        (tap < 27) ? w_stg[s * 6912 + tap * 256 + (h * 8 + j) * 16 + n] : 0.f;
    bpre[WOFF + e3] = (u16)bfrnd(val);
  }
}

// ---- Stem via MFMA implicit GEMM: merged row-load + copy-build ------------
__global__ __launch_bounds__(256, 6) void stem_mfma(
    const float* __restrict__ x, const int* __restrict__ mask,
    const u16* __restrict__ bpre, u16* __restrict__ yout,
    float* __restrict__ pool_sum, float* __restrict__ cnt)
{
  __shared__ u16 cp[8 * 1168];      // 8 shifted copies, stride 1168 u16

  const int b = blockIdx.y;
  const int u = blockIdx.x;
  const int tb = ((u & 7) << 6) | (u >> 3);   // XCD swizzle: xcd owns z-slab
  const int z0 = (tb >> 6) * 8;
  const int y0 = ((tb >> 3) & 7) * 8;
  const int x0 = (tb & 7) * 8;
  const int tid = threadIdx.x;

  if (tb == 0) {
    if (tid < 96) pool_sum[b * 96 + tid] = 0.f;
    else if (tid < 102) cnt[b * 6 + (tid - 96)] = 0.f;
  }

  const int lane = tid & 63;
  const int wv = tid >> 6;
  const int n = lane & 15;
  const int quad = lane >> 4;
  const int vy = n >> 2, vx = n & 3;

  s16x8 wf[7];
  {
    const s16x8* wfp = (const s16x8*)(bpre + 4 * 7168);
#pragma unroll
    for (int i = 0; i < 7; ++i) wf[i] = wfp[i * 64 + lane];
  }

  if (tid < 144) {
    const int lz = tid / 12, ly = tid - lz * 12;
    const int gz = z0 + lz - 2, gy = y0 + ly - 2;
    uint4* dst = (uint4*)&cp[tid * 8];
    if ((unsigned)gz < 64u && (unsigned)gy < 64u) {
      const long long rowg =
          ((long long)((b * 64 + gz) * 64 + gy)) * 64 + (x0 - 2);
      float v[12];
      if (rowg >= 0 && rowg + 12 <= (long long)NB * 64 * 64 * 64) {
        const float2* xp = (const float2*)(x + rowg);
        const int2* mp2 = (const int2*)(mask + rowg);
        float2 xv[6]; int2 mv2[6];
#pragma unroll
        for (int j = 0; j < 6; ++j) { xv[j] = xp[j]; mv2[j] = mp2[j]; }
#pragma unroll
        for (int j = 0; j < 6; ++j) {
          v[2 * j]     = xv[j].x * (float)mv2[j].x;
          v[2 * j + 1] = xv[j].y * (float)mv2[j].y;
        }
        if (x0 == 0)  { v[0] = 0.f;  v[1] = 0.f;  }
        if (x0 == 56) { v[10] = 0.f; v[11] = 0.f; }
      } else {
#pragma unroll
        for (int j = 0; j < 12; ++j) {
          const int gx = x0 - 2 + j;
          float vv = 0.f;
          if ((unsigned)gx < 64u) {
            const long long gi = rowg + j;
            vv = x[gi] * (float)mask[gi];
          }
          v[j] = vv;
        }
      }
      const u32 c0 = packbf_hw(v[0], v[1]);
      const u32 c1 = packbf_hw(v[2], v[3]);
      const u32 c2 = packbf_hw(v[4], v[5]);
      const u32 c3 = packbf_hw(v[6], v[7]);
      const u32 c4 = packbf_hw(v[8], v[9]);
      const u32 c5 = packbf_hw(v[10], v[11]);
      const u32 d0 = packbf_hw(v[1], v[2]);
      const u32 d1 = packbf_hw(v[3], v[4]);
      const u32 d2 = packbf_hw(v[5], v[6]);
      const u32 d3 = packbf_hw(v[7], v[8]);
      const u32 d4 = packbf_hw(v[9], v[10]);
      const u32 d5 = packbf_hw(v[11], 0.f);
      dst[0 * 146] = make_uint4(c0, c1, c2, c3);
      dst[1 * 146] = make_uint4(d0, d1, d2, d3);
      dst[2 * 146] = make_uint4(c1, c2, c3, c4);
      dst[3 * 146] = make_uint4(d1, d2, d3, d4);
      dst[4 * 146] = make_uint4(c2, c3, c4, c5);
      dst[5 * 146] = make_uint4(d2, d3, d4, d5);
      dst[6 * 146] = make_uint4(c3, c4, c5, 0u);
      dst[7 * 146] = make_uint4(d3, d4, d5, 0u);
    } else {
#pragma unroll
      for (int p = 0; p < 8; ++p) dst[p * 146] = make_uint4(0u, 0u, 0u, 0u);
    }
  }
  __syncthreads();

  int doff[7];
#pragma unroll
  for (int i = 0; i < 7; ++i) {
    const int r = i * 4 + quad;
    doff[i] = (r < 25) ? ((r / 5) * 12 + (r % 5)) * 8 : 0;
  }
  const int base0 = vx * 1168 + (wv * 12 + vy) * 8;
  const int gi0 = ((b * 64 + z0 + wv) * 64 + y0 + vy) * 64 + x0 + vx;
  u16* outp = yout + (size_t)gi0 * 16 + quad * 4;

  float mvc = (float)mask[gi0];
  for (int s = 0; s < 8; ++s) {
    const int sz = (s >> 2) * 4, sy2 = ((s >> 1) & 1) * 4, sx = (s & 1) * 4;
    const int off = sz * 4096 + sy2 * 64 + sx;
    float mvn = 0.f;
    if (s < 7) {
      const int s1 = s + 1;
      const int offn = ((s1 >> 2) * 4) * 4096 + (((s1 >> 1) & 1) * 4) * 64 +
                       (s1 & 1) * 4;
      mvn = (float)mask[gi0 + offn];
    }
    const int base = base0 + sx * 1168 + (sz * 12 + sy2) * 8;
    f32x4 accA = {0.f, 0.f, 0.f, 0.f};
    f32x4 accB = {0.f, 0.f, 0.f, 0.f};
#pragma unroll
    for (int i = 0; i < 7; ++i) {
      const s16x8 bf = *(const s16x8*)&cp[base + doff[i]];
      if (i & 1)
        accB = __builtin_amdgcn_mfma_f32_16x16x32_bf16(wf[i], bf, accB, 0, 0, 0);
      else
        accA = __builtin_amdgcn_mfma_f32_16x16x32_bf16(wf[i], bf, accA, 0, 0, 0);
    }
    const float f0 = fmaxf(accA[0] + accB[0], 0.f) * mvc;
    const float f1 = fmaxf(accA[1] + accB[1], 0.f) * mvc;
    const float f2 = fmaxf(accA[2] + accB[2], 0.f) * mvc;
    const float f3 = fmaxf(accA[3] + accB[3], 0.f) * mvc;
    *(uint2*)(outp + (size_t)off * 16) =
        make_uint2(packbf_hw(f0, f1), packbf_hw(f2, f3));
    mvc = mvn;
  }
}

// ---- Stages 0..2: LDS-staged implicit GEMM --------------------------------
// Output tile 4(z)x8(y)x8(x) = 256 vox (one z-plane per wave). Input region
// 9x17x17 staged to LDS in two cin-halves (44 KB), parity-split in x so the
// MFMA B-operand ds_read_b128 is stride-16B conflict-free. A = weights
// (prebuilt frags, lane&15 = cout), B = staged voxels (lane&15 = voxel),
// C row = ch / col = voxel -> direct uint2 stores, pool via shfl_xor.
template <int S>
__global__ __launch_bounds__(256, 3) void stage_lds(
    const u16* __restrict__ yin, const u16* __restrict__ bpre,
    const int* __restrict__ m_in_i, const u8* __restrict__ m_in_u8,
    u16* __restrict__ yout, u8* __restrict__ m_out,
    float* __restrict__ pool_sum, float* __restrict__ cnt, const int stage)
{
  constexpr int So = S >> 1;
  constexpr int nvox = So * So * So;
  constexpr int NTX = So / 8;              // x tiles
  constexpr int NTYX = (So / 8) * NTX;     // y*x tiles
  __shared__ u16 din[2 * 9 * 17 * 9 * 8];  // 44064 B: [p][iz 9][iy 17][ixh 9][8ch]
  __shared__ float lmp[256];
  __shared__ float lps[4][16];

  const int b = blockIdx.y;
  const int tid = threadIdx.x;
  int bxi;
  if constexpr (S == 64) {                 // producer-aligned XCD swizzle
    const int u = blockIdx.x;
    bxi = (u & 7) * 16 + (u >> 3);
  } else {
    bxi = blockIdx.x;
  }
  const int tz = bxi / NTYX;
  const int rem = bxi % NTYX;
  const int ty = rem / NTX;
  const int tx = rem % NTX;

  // ---- pooled mask: one output voxel per thread ----
  {
    const int ozl = tid >> 6, oyl = (tid >> 3) & 7, oxl = tid & 7;
    const int oz = tz * 4 + ozl, oy = ty * 8 + oyl, ox = tx * 8 + oxl;
    float mp = 0.f;
#pragma unroll
    for (int dz = 0; dz < 2; ++dz)
#pragma unroll
      for (int dy = 0; dy < 2; ++dy)
#pragma unroll
        for (int dx = 0; dx < 2; ++dx) {
          const int mi =
              ((b * S + 2 * oz + dz) * S + 2 * oy + dy) * S + 2 * ox + dx;
          const float mv = m_in_i ? (float)m_in_i[mi] : (float)m_in_u8[mi];
          mp = fmaxf(mp, mv);
        }
    lmp[tid] = mp;
    m_out[(size_t)b * nvox + (oz * So + oy) * So + ox] = (u8)mp;
  }

  const int lane = tid & 63;
  const int wv = tid >> 6;
  const int n = lane & 15;
  const int quad = lane >> 4;

  // thread-const LDS base (u16) and per-MFMA tap offsets
  // off = p*11016 + izl*1224 + iyl*72 + ixh*8 ; izl=2wv+dz, iyl=4g+2(n>>3)+dy,
  // ixh=(n&7)+(dx>>1), p=dx&1
  const int tbase = wv * 2448 + (n >> 3) * 144 + (n & 7) * 8;
  int toff[7];
#pragma unroll
  for (int i = 0; i < 7; ++i) {
    const int tap = i * 4 + quad;
    if (tap < 27) {
      const int dz = tap / 9, dy = (tap / 3) % 3, dx = tap % 3;
      toff[i] = (dx & 1) * 11016 + dz * 1224 + dy * 72 + (dx >> 1) * 8;
    } else {
      toff[i] = 0;                        // wf is zero for tap>=27
    }
  }

  f32x4 acc[4];
#pragma unroll
  for (int g = 0; g < 4; ++g) acc[g] = (f32x4){0.f, 0.f, 0.f, 0.f};

  for (int h = 0; h < 2; ++h) {          // cin halves
    __syncthreads();                     // din free (and lmp visible, h=0)
    for (int e = tid; e < 9 * 17 * 17; e += 256) {
      const int izl = e / 289;
      const int r = e - izl * 289;
      const int iyl = r / 17;
      const int ixl = r - iyl * 17;
      const int giz = tz * 8 - 1 + izl;
      const int giy = ty * 16 - 1 + iyl;
      const int gix = tx * 16 - 1 + ixl;
      uint4 v = make_uint4(0u, 0u, 0u, 0u);
      if ((unsigned)giz < (unsigned)S && (unsigned)giy < (unsigned)S &&
          (unsigned)gix < (unsigned)S) {
        const size_t a =
            ((size_t)(((b * S + giz) * S + giy) * S + gix)) * 16 + h * 8;
        v = *(const uint4*)(yin + a);
      }
      *(uint4*)&din[((((ixl & 1) * 9 + izl) * 17 + iyl) * 9 + (ixl >> 1)) * 8] = v;
    }
    __syncthreads();

    s16x8 wf[7];
    {
      const s16x8* wfp = (const s16x8*)(bpre + WOFF + stage * 7168 + h * 3584);
#pragma unroll
      for (int i = 0; i < 7; ++i) wf[i] = wfp[i * 64 + lane];
    }
#pragma unroll
    for (int i = 0; i < 7; ++i) {
      s16x8 bf[4];
#pragma unroll
      for (int g = 0; g < 4; ++g)
        bf[g] = *(const s16x8*)&din[tbase + toff[i] + g * 288];
#pragma unroll
      for (int g = 0; g < 4; ++g)
        acc[g] = __builtin_amdgcn_mfma_f32_16x16x32_bf16(wf[i], bf[g], acc[g],
                                                         0, 0, 0);
    }
  }

  // ---- epilogue: relu * mask, direct store, wave pool reduce ----
  {
    const int gbase =
        ((tz * 4 + wv) * So + ty * 8 + (n >> 3)) * So + tx * 8 + (n & 7);
    float ps0 = 0.f, ps1 = 0.f, ps2 = 0.f, ps3 = 0.f;
#pragma unroll
    for (int g = 0; g < 4; ++g) {
      const int lv = wv * 64 + g * 16 + n;
      const float mp = lmp[lv];
      const float f0 = fmaxf(acc[g][0], 0.f) * mp;
      const float f1 = fmaxf(acc[g][1], 0.f) * mp;
      const float f2 = fmaxf(acc[g][2], 0.f) * mp;
      const float f3 = fmaxf(acc[g][3], 0.f) * mp;
      const size_t gi = (size_t)b * nvox + gbase + g * 2 * So;
      *(uint2*)(yout + gi * 16 + quad * 4) =
          make_uint2(packbf_hw(f0, f1), packbf_hw(f2, f3));
      ps0 += f0; ps1 += f1; ps2 += f2; ps3 += f3;
    }
#pragma unroll
    for (int m = 1; m < 16; m <<= 1) {
      ps0 += __shfl_xor(ps0, m, 64);
      ps1 += __shfl_xor(ps1, m, 64);
      ps2 += __shfl_xor(ps2, m, 64);
      ps3 += __shfl_xor(ps3, m, 64);
    }
    if (n == 0) {
      lps[wv][quad * 4 + 0] = ps0;
      lps[wv][quad * 4 + 1] = ps1;
      lps[wv][quad * 4 + 2] = ps2;
      lps[wv][quad * 4 + 3] = ps3;
    }
  }
  __syncthreads();
  if (tid < 16) {
    const float s = lps[0][tid] + lps[1][tid] + lps[2][tid] + lps[3][tid];
    atomicAdd(&pool_sum[(b * 6 + stage) * 16 + tid], s);
  } else if (tid == 16) {
    float c = 0.f;
#pragma unroll 16
    for (int v = 0; v < 256; ++v) c += lmp[v];
    atomicAdd(&cnt[b * 6 + stage], c);
  }
}

// --------- Tail: stage 3 via MFMA (K split over 4 waves), stages 4/5 via
// split-K VALU, MLP head with parallel halves. One block per batch. ---------
__global__ __launch_bounds__(256) void tail_kernel(
    const u16* __restrict__ y3g, const u8* __restrict__ m3g,
    const u16* __restrict__ bpre,
    const float* __restrict__ wstg,
    const float* __restrict__ meta, const float* __restrict__ sched,
    const float* __restrict__ mw1, const float* __restrict__ mb1,
    const float* __restrict__ mw2, const float* __restrict__ mb2,
    const float* __restrict__ matw, const float* __restrict__ matb,
    const float* __restrict__ schw, const float* __restrict__ schb,
    const float* __restrict__ f1w, const float* __restrict__ f1b,
    const float* __restrict__ f2w, const float* __restrict__ f2b,
    const float* __restrict__ pool_sum, const float* __restrict__ cnt,
    float* __restrict__ out)
{
  const int b = blockIdx.x;
  const int t = threadIdx.x;
  __shared__ u16 ty3[8192];
  __shared__ float lm3[512];
  __shared__ float pb[4 * 64 * 17];
  __shared__ float ly4[64 * 16];
  __shared__ float lm4[64];
  __shared__ float ps4[256];
  __shared__ float ly5[8 * 16];
  __shared__ float lm5[8];
  __shared__ float ps5[128];
  __shared__ float lsum[3][16];
  __shared__ float lcnt[3];
  __shared__ float invec[112];
  __shared__ float hbuf[32];
  __shared__ float zbuf[256];
  __shared__ float psf[256];
  __shared__ float part[2];

  {
    const uint4* yb = (const uint4*)(y3g + (size_t)b * 8192);
    uint4* dst = (uint4*)ty3;
    for (int i = t; i < 1024; i += 256) dst[i] = yb[i];
    for (int i = t; i < 512; i += 256) lm3[i] = (float)m3g[b * 512 + i];
  }
  __syncthreads();

  {
    const int lane = t & 63;
    const int wv = t >> 6;
    const int mm = lane & 15;
    const int quad = lane >> 4;
    const int qh = quad >> 1, qlo = quad & 1;

    int iz0[4], iy0[4], ix0[4];
#pragma unroll
    for (int g = 0; g < 4; ++g) {
      const int vox = g * 16 + mm;
      iz0[g] = 2 * (vox >> 4) - 1;
      iy0[g] = 2 * ((vox >> 2) & 3) - 1;
      ix0[g] = 2 * (vox & 3) - 1;
    }
    f32x4 a3[4];
#pragma unroll
    for (int g = 0; g < 4; ++g) a3[g] = (f32x4){0.f, 0.f, 0.f, 0.f};
    const s16x8* bp3 = (const s16x8*)(bpre + 3 * 7168);
#pragma unroll
    for (int ii = 0; ii < 4; ++ii) {
      const int i = wv * 4 + ii;
      if (i < 14) {
        const int t0 = 2 * i, t1 = 2 * i + 1;
        const int dz0 = t0 / 9, dy0 = (t0 / 3) % 3, dx0 = t0 % 3;
        const int dz1 = (t1 < 27) ? t1 / 9 : 1;
        const int dy1 = (t1 < 27) ? (t1 / 3) % 3 : 1;
        const int dx1 = (t1 < 27) ? t1 % 3 : 1;
        const int dzq = qh ? dz1 : dz0;
        const int dyq = qh ? dy1 : dy0;
        const int dxq = qh ? dx1 : dx0;
        uint4 ar[4];
#pragma unroll
        for (int g = 0; g < 4; ++g) {
          const int iz = iz0[g] + dzq;
          const int iy = iy0[g] + dyq;
          const int ix = ix0[g] + dxq;
          const bool valid = (unsigned)iz < 8u && (unsigned)iy < 8u &&
                             (unsigned)ix < 8u;
          const int izc = min(max(iz, 0), 7);
          const int iyc = min(max(iy, 0), 7);
          const int ixc = min(max(ix, 0), 7);
          const int ad = ((izc * 8 + iyc) * 8 + ixc) * 16 + qlo * 8;
          uint4 v = *(const uint4*)&ty3[ad];
          v.x = valid ? v.x : 0u;
          v.y = valid ? v.y : 0u;
          v.z = valid ? v.z : 0u;
          v.w = valid ? v.w : 0u;
          ar[g] = v;
        }
        const s16x8 bf = bp3[i * 64 + lane];
#pragma unroll
        for (int g = 0; g < 4; ++g)
          a3[g] = __builtin_amdgcn_mfma_f32_16x16x32_bf16(
              __builtin_bit_cast(s16x8, ar[g]), bf, a3[g], 0, 0, 0);
      }
    }
#pragma unroll
    for (int g = 0; g < 4; ++g)
#pragma unroll
      for (int reg = 0; reg < 4; ++reg)
        pb[wv * 1088 + (g * 16 + quad * 4 + reg) * 17 + mm] = a3[g][reg];
  }
  __syncthreads();

  {
    const int vox = t >> 2, cg = (t & 3) * 4;
    const int oz = vox >> 4, oy = (vox >> 2) & 3, ox = vox & 3;
    float mp = 0.f;
#pragma unroll
    for (int dz = 0; dz < 2; ++dz)
#pragma unroll
      for (int dy = 0; dy < 2; ++dy)
#pragma unroll
        for (int dx = 0; dx < 2; ++dx)
          mp = fmaxf(mp, lm3[((2 * oz + dz) * 8 + 2 * oy + dy) * 8 +
                             2 * ox + dx]);
#pragma unroll
    for (int c = 0; c < 4; ++c) {
      const int ch = cg + c;
      const float s = pb[vox * 17 + ch] + pb[1088 + vox * 17 + ch] +
                      pb[2176 + vox * 17 + ch] + pb[3264 + vox * 17 + ch];
      ly4[vox * 16 + ch] = fmaxf(s, 0.f) * mp;
    }
    if (cg == 0) lm4[vox] = mp;
  }
  __syncthreads();

  if (t < 16) {
    float s = 0.f;
#pragma unroll 16
    for (int v = 0; v < 64; ++v) s += ly4[v * 16 + t];
    lsum[0][t] = s;
  } else if (t == 16) {
    float s = 0.f;
#pragma unroll 16
    for (int v = 0; v < 64; ++v) s += lm4[v];
    lcnt[0] = s;
  }
  {
    const float* w = wstg + 4 * 27 * 256;
    const int o = t >> 1, kh = t & 1;
    const int vox4 = o >> 4, co = o & 15;
    const int oz = vox4 >> 2, oy = (vox4 >> 1) & 1, ox = vox4 & 1;
    float acc = 0.f;
#pragma unroll
    for (int tt = 0; tt < 14; ++tt) {
      const int tap = tt + (kh ? 14 : 0);
      if (tap < 27) {
        const int dz = tap / 9, dy = (tap / 3) % 3, dx = tap % 3;
        const int iz = 2 * oz + dz - 1, iy = 2 * oy + dy - 1,
                  ix = 2 * ox + dx - 1;
        const float s = ((unsigned)iz < 4u && (unsigned)iy < 4u &&
                         (unsigned)ix < 4u) ? 1.f : 0.f;
        const int idx = ((min(max(iz, 0), 3) * 4 + min(max(iy, 0), 3)) * 4 +
                         min(max(ix, 0), 3)) * 16;
        const float* wp = w + tap * 256 + co;
#pragma unroll
        for (int ci = 0; ci < 16; ++ci)
          acc = fmaf(ly4[idx + ci] * s, wp[ci * 16], acc);
      }
    }
    ps4[t] = acc;
  }
  __syncthreads();

  if (t < 128) {
    const int vox4 = t >> 4, co = t & 15;
    float mp = 0.f;
#pragma unroll
    for (int dz = 0; dz < 2; ++dz)
#pragma unroll
      for (int dy = 0; dy < 2; ++dy)
#pragma unroll
        for (int dx = 0; dx < 2; ++dx)
          mp = fmaxf(mp, lm4[((2 * (vox4 >> 2) + dz) * 4 +
                              2 * ((vox4 >> 1) & 1) + dy) * 4 +
                             2 * (vox4 & 1) + dx]);
    ly5[t] = fmaxf(ps4[2 * t] + ps4[2 * t + 1], 0.f) * mp;
    if (co == 0) lm5[vox4] = mp;
  }
  __syncthreads();

  if (t < 16) {
    float s = 0.f;
#pragma unroll
    for (int v = 0; v < 8; ++v) s += ly5[v * 16 + t];
    lsum[1][t] = s;
  } else if (t == 16) {
    lcnt[1] = lm5[0] + lm5[1] + lm5[2] + lm5[3] + lm5[4] + lm5[5] + lm5[6] +
              lm5[7];
  }
  if (t < 128) {
    const float* w = wstg + 5 * 27 * 256;
    const int co = t & 15, k8 = t >> 4;
    float acc = 0.f;
#pragma unroll
    for (int tt = 0; tt < 4; ++tt) {
      const int tap = k8 * 4 + tt;
      if (tap < 27) {
        const int dz = tap / 9, dy = (tap / 3) % 3, dx = tap % 3;
        const int iz = dz - 1, iy = dy - 1, ix = dx - 1;
        const float s = ((unsigned)iz < 2u && (unsigned)iy < 2u &&
                         (unsigned)ix < 2u) ? 1.f : 0.f;
        const int idx = ((min(max(iz, 0), 1) * 2 + min(max(iy, 0), 1)) * 2 +
                         min(max(ix, 0), 1)) * 16;
        const float* wp = w + tap * 256 + co;
#pragma unroll
        for (int ci = 0; ci < 16; ++ci)
          acc = fmaf(ly5[idx + ci] * s, wp[ci * 16], acc);
      }
    }
    ps5[t] = acc;
  }
  __syncthreads();

  if (t < 16) {
    float s = ps5[t] + ps5[16 + t] + ps5[32 + t] + ps5[48 + t] +
              ps5[64 + t] + ps5[80 + t] + ps5[96 + t] + ps5[112 + t];
    float mp = 0.f;
#pragma unroll
    for (int v = 0; v < 8; ++v) mp = fmaxf(mp, lm5[v]);
    lsum[2][t] = fmaxf(s, 0.f) * mp;
    if (t == 0) lcnt[2] = mp;
  } else if (t >= 96 && t < 128) {
    const int j = t - 96;
    float h = mb1[j];
#pragma unroll
    for (int k = 0; k < 3; ++k) h = fmaf(meta[b * 3 + k], mw1[k * 32 + j], h);
    hbuf[j] = fmaxf(h, 0.f);
  }
  __syncthreads();

  if (t < 48) {
    const int s = t >> 4;
    invec[t] = pool_sum[b * 96 + t] / fmaxf(cnt[b * 6 + s], 1.f);
  } else if (t < 96) {
    const int s = (t >> 4) - 3;
    invec[t] = lsum[s][t & 15] / fmaxf(lcnt[s], 1.f);
  } else if (t < 112) {
    const int j = t - 96;
    float e = mb2[j];
#pragma unroll
    for (int k = 0; k < 32; ++k) e = fmaf(hbuf[k], mw2[k * 16 + j], e);
    invec[t] = e;
  }
  __syncthreads();

  if (t < 128) {
    float a = matb[t];
#pragma unroll 16
    for (int k = 0; k < 112; ++k) a = fmaf(invec[k], matw[k * 128 + t], a);
    zbuf[t] = fmaxf(a, 0.f);
  } else {
    const int c = t - 128;
    float s = schb[c];
#pragma unroll 16
    for (int k = 0; k < 128; ++k)
      s = fmaf(sched[b * 128 + k], schw[k * 128 + c], s);
    zbuf[128 + c] = fmaxf(s, 0.f);
  }
  __syncthreads();

  {
    const int col = t & 127, kh = t >> 7;
    float a = 0.f;
#pragma unroll 16
    for (int kk = 0; kk < 128; ++kk) {
      const int k = kh * 128 + kk;
      a = fmaf(zbuf[k], f1w[k * 128 + col], a);
    }
    psf[t] = a;
  }
  __syncthreads();

  if (t < 128) {
    const float a = psf[t] + psf[128 + t] + f1b[t];
    float v = fmaxf(a, 0.f) * f2w[t];
#pragma unroll
    for (int off = 32; off > 0; off >>= 1) v += __shfl_xor(v, off, 64);
    if ((t & 63) == 0) part[t >> 6] = v;
  }
  __syncthreads();
  if (t == 0) out[b] = part[0] + part[1] + f2b[0];
}

extern "C" void kernel_launch(void* const* d_in, const int* in_sizes, int n_in,
                              void* d_out, int out_size, void* d_ws,
                              size_t ws_size, hipStream_t stream)
{
  (void)in_sizes; (void)n_in; (void)out_size; (void)ws_size;
  const float* x      = (const float*)d_in[0];
  const int*   mask   = (const int*)  d_in[1];
  const float* meta   = (const float*)d_in[2];
  const float* sched  = (const float*)d_in[3];
  const float* w_stem = (const float*)d_in[4];
  const float* w_stg  = (const float*)d_in[5];
  const float* mw1    = (const float*)d_in[6];
  const float* mb1    = (const float*)d_in[7];
  const float* mw2    = (const float*)d_in[8];
  const float* mb2    = (const float*)d_in[9];
  const float* matw   = (const float*)d_in[10];
  const float* matb   = (const float*)d_in[11];
  const float* schw   = (const float*)d_in[12];
  const float* schb   = (const float*)d_in[13];
  const float* f1w    = (const float*)d_in[14];
  const float* f1b    = (const float*)d_in[15];
  const float* f2w    = (const float*)d_in[16];
  const float* f2b    = (const float*)d_in[17];
  float* out = (float*)d_out;

  char* ws = (char*)d_ws;
  size_t off = 0;
  auto alloc = [&](size_t nbytes) -> void* {
    void* p = ws + off;
    off += (nbytes + 255) & ~(size_t)255;
    return p;
  };

  u16* y0 = (u16*)alloc((size_t)NB * 64 * 64 * 64 * CH * 2);
  u16* y1 = (u16*)alloc((size_t)NB * 32 * 32 * 32 * CH * 2);
  u16* y2 = (u16*)alloc((size_t)NB * 16 * 16 * 16 * CH * 2);
  u16* y3 = (u16*)alloc((size_t)NB * 8 * 8 * 8 * CH * 2);
  u8* m1 = (u8*)alloc((size_t)NB * 32 * 32 * 32);
  u8* m2 = (u8*)alloc((size_t)NB * 16 * 16 * 16);
  u8* m3 = (u8*)alloc((size_t)NB * 8 * 8 * 8);
  float* pool_sum = (float*)alloc((NB * 96 + NB * 6) * 4);
  float* cnt = pool_sum + NB * 96;
  u16* bpre = (u16*)alloc((size_t)WPRE_TOT * 2);

  bprep_kernel<<<(WPRE_TOT + 255) / 256, 256, 0, stream>>>(w_stg, w_stem,
                                                           bpre);

  stem_mfma<<<dim3(512, NB), 256, 0, stream>>>(x, mask, bpre, y0,
                                               pool_sum, cnt);

  // stage 0: 64->32 (128 tiles/batch of 4x8x8)
  stage_lds<64><<<dim3(128, NB), 256, 0, stream>>>(
      y0, bpre, mask, (const u8*)nullptr, y1, m1, pool_sum, cnt, 0);
  // stage 1: 32->16 (16 tiles/batch)
  stage_lds<32><<<dim3(16, NB), 256, 0, stream>>>(
      y1, bpre, (const int*)nullptr, m1, y2, m2, pool_sum, cnt, 1);
  // stage 2: 16->8 (2 tiles/batch)
  stage_lds<16><<<dim3(2, NB), 256, 0, stream>>>(
      y2, bpre, (const int*)nullptr, m2, y3, m3, pool_sum, cnt, 2);

  tail_kernel<<<NB, 256, 0, stream>>>(y3, m3, bpre, w_stg, meta, sched,
                                      mw1, mb1, mw2, mb2, matw, matb,
                                      schw, schb, f1w, f1b, f2w, f2b,
                                      pool_sum, cnt, out);
}

// Round 7
// 194.616 us; speedup vs baseline: 1.0787x; 1.0787x over previous
//
#include <hip/hip_runtime.h>

#define CH 16
#define NB 8

typedef unsigned short u16;
typedef unsigned char u8;
typedef unsigned int u32;
typedef __attribute__((ext_vector_type(8))) short s16x8;
typedef __attribute__((ext_vector_type(4))) float f32x4;

__device__ __forceinline__ float bflo(u32 u) { return __uint_as_float(u << 16); }
__device__ __forceinline__ float bfhi(u32 u) { return __uint_as_float(u & 0xffff0000u); }
__device__ __forceinline__ u32 bfrnd(float f) {
  u32 u = __float_as_uint(f);
  return (u + 0x7fffu + ((u >> 16) & 1u)) >> 16;
}
// HW packed f32->bf16 RNE convert: 1 VALU inst, bit-identical to bfrnd for
// finite inputs.
__device__ __forceinline__ u32 packbf_hw(float lo, float hi) {
  u32 r;
  asm("v_cvt_pk_bf16_f32 %0, %1, %2" : "=v"(r) : "v"(lo), "v"(hi));
  return r;
}

// ---- Prep: bf16 B-fragments for MFMA stages 0..3 + stem A-fragments -------
// bpre layout: [0 .. 4*7168)  : stage 0..3 B-fragments
//              [4*7168 .. +3584): stem weight fragments [i=0..6][lane][j]
__global__ __launch_bounds__(256) void bprep_kernel(
    const float* __restrict__ w_stg, const float* __restrict__ w_stem,
    u16* __restrict__ bpre)
{
  const int e = blockIdx.x * 256 + (int)threadIdx.x;
  if (e >= 4 * 7168 + 3584) return;
  if (e < 4 * 7168) {
    const int s = e / 7168, r0 = e % 7168;
    const int i = r0 >> 9;
    const int r = r0 & 511;
    const int l = r >> 3, j = r & 7;
    const int tap = 2 * i + (l >> 5);
    const int cin = ((l >> 4) & 1) * 8 + j;
    const int n = l & 15;
    const float* w = w_stg + s * 27 * 256;
    const float val = (tap < 27) ? w[(tap * 16 + cin) * 16 + n] : 0.f;
    bpre[s * 7168 + i * 512 + l * 8 + j] = (u16)bfrnd(val);
  } else {
    const int e2 = e - 4 * 7168;          // [i][lane][j]
    const int i = e2 >> 9;
    const int r0 = e2 & 511;
    const int lane = r0 >> 3, j = r0 & 7;
    const int quad = lane >> 4, n = lane & 15;
    const int r = i * 4 + quad;
    const float val = (r < 25 && j < 5) ? w_stem[(r * 5 + j) * 16 + n] : 0.f;
    bpre[4 * 7168 + e2] = (u16)bfrnd(val);
  }
}

// ---- Stem via MFMA implicit GEMM: merged row-load + copy-build ------------
__global__ __launch_bounds__(256, 6) void stem_mfma(
    const float* __restrict__ x, const int* __restrict__ mask,
    const u16* __restrict__ bpre, u16* __restrict__ yout,
    float* __restrict__ pool_sum, float* __restrict__ cnt)
{
  __shared__ u16 cp[8 * 1168];      // 8 shifted copies, stride 1168 u16

  const int b = blockIdx.y;
  const int u = blockIdx.x;
  const int tb = ((u & 7) << 6) | (u >> 3);   // XCD swizzle: xcd owns z-slab
  const int z0 = (tb >> 6) * 8;
  const int y0 = ((tb >> 3) & 7) * 8;
  const int x0 = (tb & 7) * 8;
  const int tid = threadIdx.x;

  if (tb == 0) {
    if (tid < 96) pool_sum[b * 96 + tid] = 0.f;
    else if (tid < 102) cnt[b * 6 + (tid - 96)] = 0.f;
  }

  const int lane = tid & 63;
  const int wv = tid >> 6;
  const int n = lane & 15;
  const int quad = lane >> 4;
  const int vy = n >> 2, vx = n & 3;

  s16x8 wf[7];
  {
    const s16x8* wfp = (const s16x8*)(bpre + 4 * 7168);
#pragma unroll
    for (int i = 0; i < 7; ++i) wf[i] = wfp[i * 64 + lane];
  }

  if (tid < 144) {
    const int lz = tid / 12, ly = tid - lz * 12;
    const int gz = z0 + lz - 2, gy = y0 + ly - 2;
    uint4* dst = (uint4*)&cp[tid * 8];
    if ((unsigned)gz < 64u && (unsigned)gy < 64u) {
      const long long rowg =
          ((long long)((b * 64 + gz) * 64 + gy)) * 64 + (x0 - 2);
      float v[12];
      if (rowg >= 0 && rowg + 12 <= (long long)NB * 64 * 64 * 64) {
        const float2* xp = (const float2*)(x + rowg);
        const int2* mp2 = (const int2*)(mask + rowg);
        float2 xv[6]; int2 mv2[6];
#pragma unroll
        for (int j = 0; j < 6; ++j) { xv[j] = xp[j]; mv2[j] = mp2[j]; }
#pragma unroll
        for (int j = 0; j < 6; ++j) {
          v[2 * j]     = xv[j].x * (float)mv2[j].x;
          v[2 * j + 1] = xv[j].y * (float)mv2[j].y;
        }
        if (x0 == 0)  { v[0] = 0.f;  v[1] = 0.f;  }
        if (x0 == 56) { v[10] = 0.f; v[11] = 0.f; }
      } else {
#pragma unroll
        for (int j = 0; j < 12; ++j) {
          const int gx = x0 - 2 + j;
          float vv = 0.f;
          if ((unsigned)gx < 64u) {
            const long long gi = rowg + j;
            vv = x[gi] * (float)mask[gi];
          }
          v[j] = vv;
        }
      }
      const u32 c0 = packbf_hw(v[0], v[1]);
      const u32 c1 = packbf_hw(v[2], v[3]);
      const u32 c2 = packbf_hw(v[4], v[5]);
      const u32 c3 = packbf_hw(v[6], v[7]);
      const u32 c4 = packbf_hw(v[8], v[9]);
      const u32 c5 = packbf_hw(v[10], v[11]);
      const u32 d0 = packbf_hw(v[1], v[2]);
      const u32 d1 = packbf_hw(v[3], v[4]);
      const u32 d2 = packbf_hw(v[5], v[6]);
      const u32 d3 = packbf_hw(v[7], v[8]);
      const u32 d4 = packbf_hw(v[9], v[10]);
      const u32 d5 = packbf_hw(v[11], 0.f);
      dst[0 * 146] = make_uint4(c0, c1, c2, c3);
      dst[1 * 146] = make_uint4(d0, d1, d2, d3);
      dst[2 * 146] = make_uint4(c1, c2, c3, c4);
      dst[3 * 146] = make_uint4(d1, d2, d3, d4);
      dst[4 * 146] = make_uint4(c2, c3, c4, c5);
      dst[5 * 146] = make_uint4(d2, d3, d4, d5);
      dst[6 * 146] = make_uint4(c3, c4, c5, 0u);
      dst[7 * 146] = make_uint4(d3, d4, d5, 0u);
    } else {
#pragma unroll
      for (int p = 0; p < 8; ++p) dst[p * 146] = make_uint4(0u, 0u, 0u, 0u);
    }
  }
  __syncthreads();

  int doff[7];
#pragma unroll
  for (int i = 0; i < 7; ++i) {
    const int r = i * 4 + quad;
    doff[i] = (r < 25) ? ((r / 5) * 12 + (r % 5)) * 8 : 0;
  }
  const int base0 = vx * 1168 + (wv * 12 + vy) * 8;
  const int gi0 = ((b * 64 + z0 + wv) * 64 + y0 + vy) * 64 + x0 + vx;
  u16* outp = yout + (size_t)gi0 * 16 + quad * 4;

  float mvc = (float)mask[gi0];
  for (int s = 0; s < 8; ++s) {
    const int sz = (s >> 2) * 4, sy2 = ((s >> 1) & 1) * 4, sx = (s & 1) * 4;
    const int off = sz * 4096 + sy2 * 64 + sx;
    float mvn = 0.f;
    if (s < 7) {
      const int s1 = s + 1;
      const int offn = ((s1 >> 2) * 4) * 4096 + (((s1 >> 1) & 1) * 4) * 64 +
                       (s1 & 1) * 4;
      mvn = (float)mask[gi0 + offn];
    }
    const int base = base0 + sx * 1168 + (sz * 12 + sy2) * 8;
    f32x4 accA = {0.f, 0.f, 0.f, 0.f};
    f32x4 accB = {0.f, 0.f, 0.f, 0.f};
#pragma unroll
    for (int i = 0; i < 7; ++i) {
      const s16x8 bf = *(const s16x8*)&cp[base + doff[i]];
      if (i & 1)
        accB = __builtin_amdgcn_mfma_f32_16x16x32_bf16(wf[i], bf, accB, 0, 0, 0);
      else
        accA = __builtin_amdgcn_mfma_f32_16x16x32_bf16(wf[i], bf, accA, 0, 0, 0);
    }
    const float f0 = fmaxf(accA[0] + accB[0], 0.f) * mvc;
    const float f1 = fmaxf(accA[1] + accB[1], 0.f) * mvc;
    const float f2 = fmaxf(accA[2] + accB[2], 0.f) * mvc;
    const float f3 = fmaxf(accA[3] + accB[3], 0.f) * mvc;
    *(uint2*)(outp + (size_t)off * 16) =
        make_uint2(packbf_hw(f0, f1), packbf_hw(f2, f3));
    mvc = mvn;
  }
}

// ---- Stages 0..2: MFMA implicit GEMM, swapped operands ---------------------
// mfma(A=weights from lb, B=gathered voxels): A and B lane layouts are
// identical, so the SAME lb fragment and the SAME data gather serve the
// swapped roles; products/sums are bit-identical. C becomes row=cout,
// col=voxel -> each lane holds 4 consecutive channels of one voxel ->
// direct coalesced uint2 stores, shfl_xor pool reduce. No lC buffer,
// no per-group barriers (was 8 barriers + 2K LDS ops per block).
template <int S>
__global__ __launch_bounds__(256) void stage_mfma4(
    const u16* __restrict__ yin, const u16* __restrict__ bpre,
    const int* __restrict__ m_in_i, const u8* __restrict__ m_in_u8,
    u16* __restrict__ yout, u8* __restrict__ m_out,
    float* __restrict__ pool_sum, float* __restrict__ cnt,
    const int stage)
{
  __shared__ u16 lb[14 * 512];
  __shared__ float lmp[256];
  __shared__ float lps[4][16];

  constexpr int So = S >> 1;
  constexpr int nvox = So * So * So;
  constexpr int NBX = nvox / 256;
  const int b = blockIdx.y;
  const int tid = threadIdx.x;
  const int u = blockIdx.x;
  int bxi;
  if constexpr (NBX >= 8) bxi = (u & 7) * (NBX / 8) + (u >> 3);
  else bxi = u;
  const int vg0 = bxi * 256;

  {
    const uint4* src = (const uint4*)bpre;
    uint4* dst = (uint4*)lb;
    for (int e = tid; e < 896; e += 256) dst[e] = src[e];
  }

  {
    const int vox = vg0 + tid;
    const int oz = vox / (So * So);
    const int oy = (vox / So) % So;
    const int ox = vox % So;
    float mp = 0.f;
#pragma unroll
    for (int dz = 0; dz < 2; ++dz)
#pragma unroll
      for (int dy = 0; dy < 2; ++dy)
#pragma unroll
        for (int dx = 0; dx < 2; ++dx) {
          const int mi =
              ((b * S + 2 * oz + dz) * S + 2 * oy + dy) * S + 2 * ox + dx;
          const float mv = m_in_i ? (float)m_in_i[mi] : (float)m_in_u8[mi];
          mp = fmaxf(mp, mv);
        }
    lmp[tid] = mp;
  }
  __syncthreads();

  const int wv = tid >> 6;
  const int lane = tid & 63;
  const int m = lane & 15;
  const int quad = lane >> 4;
  const int qh = quad >> 1;
  const int qlo = quad & 1;

  int izb[4], iyb[4], ixb[4];
#pragma unroll
  for (int g = 0; g < 4; ++g) {
    const int vox = vg0 + wv * 64 + g * 16 + m;
    const int oz = vox / (So * So);
    const int oy = (vox / So) % So;
    const int ox = vox % So;
    izb[g] = 2 * oz - 1;
    iyb[g] = 2 * oy - 1;
    ixb[g] = 2 * ox - 1;
  }

  const s16x8* lbv = (const s16x8*)lb;
  f32x4 acc[4];
#pragma unroll
  for (int g = 0; g < 4; ++g) acc[g] = (f32x4){0.f, 0.f, 0.f, 0.f};

#pragma unroll
  for (int i = 0; i < 14; ++i) {
    const int t0 = 2 * i, t1 = 2 * i + 1;
    const int dz0 = t0 / 9, dy0 = (t0 / 3) % 3, dx0 = t0 % 3;
    const int dz1 = (t1 < 27) ? t1 / 9 : 1;
    const int dy1 = (t1 < 27) ? (t1 / 3) % 3 : 1;
    const int dx1 = (t1 < 27) ? t1 % 3 : 1;
    const int dzq = qh ? dz1 : dz0;
    const int dyq = qh ? dy1 : dy0;
    const int dxq = qh ? dx1 : dx0;

    uint4 ar[4];
#pragma unroll
    for (int g = 0; g < 4; ++g) {
      const int iz = izb[g] + dzq;
      const int iy = iyb[g] + dyq;
      const int ix = ixb[g] + dxq;
      const bool valid = (unsigned)iz < (unsigned)S &&
                         (unsigned)iy < (unsigned)S &&
                         (unsigned)ix < (unsigned)S;
      const int izc = min(max(iz, 0), S - 1);
      const int iyc = min(max(iy, 0), S - 1);
      const int ixc = min(max(ix, 0), S - 1);
      const size_t addr =
          (size_t)(((b * S + izc) * S + iyc) * S + ixc) * 16 + qlo * 8;
      uint4 v = *(const uint4*)(yin + addr);
      v.x = valid ? v.x : 0u;
      v.y = valid ? v.y : 0u;
      v.z = valid ? v.z : 0u;
      v.w = valid ? v.w : 0u;
      ar[g] = v;
    }
    const s16x8 bfrag = lbv[i * 64 + lane];
    // swapped operands: A = weights (row = cout), B = data (col = voxel)
#pragma unroll
    for (int g = 0; g < 4; ++g)
      acc[g] = __builtin_amdgcn_mfma_f32_16x16x32_bf16(
          bfrag, __builtin_bit_cast(s16x8, ar[g]), acc[g], 0, 0, 0);
  }

  // epilogue: relu * mask, direct coalesced store, wave pool reduce
  {
    float ps0 = 0.f, ps1 = 0.f, ps2 = 0.f, ps3 = 0.f;
#pragma unroll
    for (int g = 0; g < 4; ++g) {
      const int lv = wv * 64 + g * 16 + m;
      const float mp = lmp[lv];
      const float f0 = fmaxf(acc[g][0], 0.f) * mp;
      const float f1 = fmaxf(acc[g][1], 0.f) * mp;
      const float f2 = fmaxf(acc[g][2], 0.f) * mp;
      const float f3 = fmaxf(acc[g][3], 0.f) * mp;
      const size_t gi = (size_t)b * nvox + vg0 + lv;
      *(uint2*)(yout + gi * 16 + quad * 4) =
          make_uint2(packbf_hw(f0, f1), packbf_hw(f2, f3));
      if (quad == 0) m_out[gi] = (u8)mp;
      ps0 += f0; ps1 += f1; ps2 += f2; ps3 += f3;
    }
#pragma unroll
    for (int mm = 1; mm < 16; mm <<= 1) {
      ps0 += __shfl_xor(ps0, mm, 64);
      ps1 += __shfl_xor(ps1, mm, 64);
      ps2 += __shfl_xor(ps2, mm, 64);
      ps3 += __shfl_xor(ps3, mm, 64);
    }
    if (m == 0) {
      lps[wv][quad * 4 + 0] = ps0;
      lps[wv][quad * 4 + 1] = ps1;
      lps[wv][quad * 4 + 2] = ps2;
      lps[wv][quad * 4 + 3] = ps3;
    }
  }
  __syncthreads();
  if (tid < 16) {
    const float s = lps[0][tid] + lps[1][tid] + lps[2][tid] + lps[3][tid];
    atomicAdd(&pool_sum[(b * 6 + stage) * 16 + tid], s);
  } else if (tid == 16) {
    float c = 0.f;
#pragma unroll 16
    for (int v = 0; v < 256; ++v) c += lmp[v];
    atomicAdd(&cnt[b * 6 + stage], c);
  }
}

// --------- Tail: stage 3 via MFMA (K split over 4 waves), stages 4/5 via
// split-K VALU, MLP head with parallel halves. One block per batch. ---------
__global__ __launch_bounds__(256) void tail_kernel(
    const u16* __restrict__ y3g, const u8* __restrict__ m3g,
    const u16* __restrict__ bpre,
    const float* __restrict__ wstg,
    const float* __restrict__ meta, const float* __restrict__ sched,
    const float* __restrict__ mw1, const float* __restrict__ mb1,
    const float* __restrict__ mw2, const float* __restrict__ mb2,
    const float* __restrict__ matw, const float* __restrict__ matb,
    const float* __restrict__ schw, const float* __restrict__ schb,
    const float* __restrict__ f1w, const float* __restrict__ f1b,
    const float* __restrict__ f2w, const float* __restrict__ f2b,
    const float* __restrict__ pool_sum, const float* __restrict__ cnt,
    float* __restrict__ out)
{
  const int b = blockIdx.x;
  const int t = threadIdx.x;
  __shared__ u16 ty3[8192];
  __shared__ float lm3[512];
  __shared__ float pb[4 * 64 * 17];
  __shared__ float ly4[64 * 16];
  __shared__ float lm4[64];
  __shared__ float ps4[256];
  __shared__ float ly5[8 * 16];
  __shared__ float lm5[8];
  __shared__ float ps5[128];
  __shared__ float lsum[3][16];
  __shared__ float lcnt[3];
  __shared__ float invec[112];
  __shared__ float hbuf[32];
  __shared__ float zbuf[256];
  __shared__ float psf[256];
  __shared__ float part[2];

  {
    const uint4* yb = (const uint4*)(y3g + (size_t)b * 8192);
    uint4* dst = (uint4*)ty3;
    for (int i = t; i < 1024; i += 256) dst[i] = yb[i];
    for (int i = t; i < 512; i += 256) lm3[i] = (float)m3g[b * 512 + i];
  }
  __syncthreads();

  {
    const int lane = t & 63;
    const int wv = t >> 6;
    const int mm = lane & 15;
    const int quad = lane >> 4;
    const int qh = quad >> 1, qlo = quad & 1;

    int iz0[4], iy0[4], ix0[4];
#pragma unroll
    for (int g = 0; g < 4; ++g) {
      const int vox = g * 16 + mm;
      iz0[g] = 2 * (vox >> 4) - 1;
      iy0[g] = 2 * ((vox >> 2) & 3) - 1;
      ix0[g] = 2 * (vox & 3) - 1;
    }
    f32x4 a3[4];
#pragma unroll
    for (int g = 0; g < 4; ++g) a3[g] = (f32x4){0.f, 0.f, 0.f, 0.f};
    const s16x8* bp3 = (const s16x8*)(bpre + 3 * 7168);
#pragma unroll
    for (int ii = 0; ii < 4; ++ii) {
      const int i = wv * 4 + ii;
      if (i < 14) {
        const int t0 = 2 * i, t1 = 2 * i + 1;
        const int dz0 = t0 / 9, dy0 = (t0 / 3) % 3, dx0 = t0 % 3;
        const int dz1 = (t1 < 27) ? t1 / 9 : 1;
        const int dy1 = (t1 < 27) ? (t1 / 3) % 3 : 1;
        const int dx1 = (t1 < 27) ? t1 % 3 : 1;
        const int dzq = qh ? dz1 : dz0;
        const int dyq = qh ? dy1 : dy0;
        const int dxq = qh ? dx1 : dx0;
        uint4 ar[4];
#pragma unroll
        for (int g = 0; g < 4; ++g) {
          const int iz = iz0[g] + dzq;
          const int iy = iy0[g] + dyq;
          const int ix = ix0[g] + dxq;
          const bool valid = (unsigned)iz < 8u && (unsigned)iy < 8u &&
                             (unsigned)ix < 8u;
          const int izc = min(max(iz, 0), 7);
          const int iyc = min(max(iy, 0), 7);
          const int ixc = min(max(ix, 0), 7);
          const int ad = ((izc * 8 + iyc) * 8 + ixc) * 16 + qlo * 8;
          uint4 v = *(const uint4*)&ty3[ad];
          v.x = valid ? v.x : 0u;
          v.y = valid ? v.y : 0u;
          v.z = valid ? v.z : 0u;
          v.w = valid ? v.w : 0u;
          ar[g] = v;
        }
        const s16x8 bf = bp3[i * 64 + lane];
#pragma unroll
        for (int g = 0; g < 4; ++g)
          a3[g] = __builtin_amdgcn_mfma_f32_16x16x32_bf16(
              __builtin_bit_cast(s16x8, ar[g]), bf, a3[g], 0, 0, 0);
      }
    }
#pragma unroll
    for (int g = 0; g < 4; ++g)
#pragma unroll
      for (int reg = 0; reg < 4; ++reg)
        pb[wv * 1088 + (g * 16 + quad * 4 + reg) * 17 + mm] = a3[g][reg];
  }
  __syncthreads();

  {
    const int vox = t >> 2, cg = (t & 3) * 4;
    const int oz = vox >> 4, oy = (vox >> 2) & 3, ox = vox & 3;
    float mp = 0.f;
#pragma unroll
    for (int dz = 0; dz < 2; ++dz)
#pragma unroll
      for (int dy = 0; dy < 2; ++dy)
#pragma unroll
        for (int dx = 0; dx < 2; ++dx)
          mp = fmaxf(mp, lm3[((2 * oz + dz) * 8 + 2 * oy + dy) * 8 +
                             2 * ox + dx]);
#pragma unroll
    for (int c = 0; c < 4; ++c) {
      const int ch = cg + c;
      const float s = pb[vox * 17 + ch] + pb[1088 + vox * 17 + ch] +
                      pb[2176 + vox * 17 + ch] + pb[3264 + vox * 17 + ch];
      ly4[vox * 16 + ch] = fmaxf(s, 0.f) * mp;
    }
    if (cg == 0) lm4[vox] = mp;
  }
  __syncthreads();

  if (t < 16) {
    float s = 0.f;
#pragma unroll 16
    for (int v = 0; v < 64; ++v) s += ly4[v * 16 + t];
    lsum[0][t] = s;
  } else if (t == 16) {
    float s = 0.f;
#pragma unroll 16
    for (int v = 0; v < 64; ++v) s += lm4[v];
    lcnt[0] = s;
  }
  {
    const float* w = wstg + 4 * 27 * 256;
    const int o = t >> 1, kh = t & 1;
    const int vox4 = o >> 4, co = o & 15;
    const int oz = vox4 >> 2, oy = (vox4 >> 1) & 1, ox = vox4 & 1;
    float acc = 0.f;
#pragma unroll
    for (int tt = 0; tt < 14; ++tt) {
      const int tap = tt + (kh ? 14 : 0);
      if (tap < 27) {
        const int dz = tap / 9, dy = (tap / 3) % 3, dx = tap % 3;
        const int iz = 2 * oz + dz - 1, iy = 2 * oy + dy - 1,
                  ix = 2 * ox + dx - 1;
        const float s = ((unsigned)iz < 4u && (unsigned)iy < 4u &&
                         (unsigned)ix < 4u) ? 1.f : 0.f;
        const int idx = ((min(max(iz, 0), 3) * 4 + min(max(iy, 0), 3)) * 4 +
                         min(max(ix, 0), 3)) * 16;
        const float* wp = w + tap * 256 + co;
#pragma unroll
        for (int ci = 0; ci < 16; ++ci)
          acc = fmaf(ly4[idx + ci] * s, wp[ci * 16], acc);
      }
    }
    ps4[t] = acc;
  }
  __syncthreads();

  if (t < 128) {
    const int vox4 = t >> 4, co = t & 15;
    float mp = 0.f;
#pragma unroll
    for (int dz = 0; dz < 2; ++dz)
#pragma unroll
      for (int dy = 0; dy < 2; ++dy)
#pragma unroll
        for (int dx = 0; dx < 2; ++dx)
          mp = fmaxf(mp, lm4[((2 * (vox4 >> 2) + dz) * 4 +
                              2 * ((vox4 >> 1) & 1) + dy) * 4 +
                             2 * (vox4 & 1) + dx]);
    ly5[t] = fmaxf(ps4[2 * t] + ps4[2 * t + 1], 0.f) * mp;
    if (co == 0) lm5[vox4] = mp;
  }
  __syncthreads();

  if (t < 16) {
    float s = 0.f;
#pragma unroll
    for (int v = 0; v < 8; ++v) s += ly5[v * 16 + t];
    lsum[1][t] = s;
  } else if (t == 16) {
    lcnt[1] = lm5[0] + lm5[1] + lm5[2] + lm5[3] + lm5[4] + lm5[5] + lm5[6] +
              lm5[7];
  }
  if (t < 128) {
    const float* w = wstg + 5 * 27 * 256;
    const int co = t & 15, k8 = t >> 4;
    float acc = 0.f;
#pragma unroll
    for (int tt = 0; tt < 4; ++tt) {
      const int tap = k8 * 4 + tt;
      if (tap < 27) {
        const int dz = tap / 9, dy = (tap / 3) % 3, dx = tap % 3;
        const int iz = dz - 1, iy = dy - 1, ix = dx - 1;
        const float s = ((unsigned)iz < 2u && (unsigned)iy < 2u &&
                         (unsigned)ix < 2u) ? 1.f : 0.f;
        const int idx = ((min(max(iz, 0), 1) * 2 + min(max(iy, 0), 1)) * 2 +
                         min(max(ix, 0), 1)) * 16;
        const float* wp = w + tap * 256 + co;
#pragma unroll
        for (int ci = 0; ci < 16; ++ci)
          acc = fmaf(ly5[idx + ci] * s, wp[ci * 16], acc);
      }
    }
    ps5[t] = acc;
  }
  __syncthreads();

  if (t < 16) {
    float s = ps5[t] + ps5[16 + t] + ps5[32 + t] + ps5[48 + t] +
              ps5[64 + t] + ps5[80 + t] + ps5[96 + t] + ps5[112 + t];
    float mp = 0.f;
#pragma unroll
    for (int v = 0; v < 8; ++v) mp = fmaxf(mp, lm5[v]);
    lsum[2][t] = fmaxf(s, 0.f) * mp;
    if (t == 0) lcnt[2] = mp;
  } else if (t >= 96 && t < 128) {
    const int j = t - 96;
    float h = mb1[j];
#pragma unroll
    for (int k = 0; k < 3; ++k) h = fmaf(meta[b * 3 + k], mw1[k * 32 + j], h);
    hbuf[j] = fmaxf(h, 0.f);
  }
  __syncthreads();

  if (t < 48) {
    const int s = t >> 4;
    invec[t] = pool_sum[b * 96 + t] / fmaxf(cnt[b * 6 + s], 1.f);
  } else if (t < 96) {
    const int s = (t >> 4) - 3;
    invec[t] = lsum[s][t & 15] / fmaxf(lcnt[s], 1.f);
  } else if (t < 112) {
    const int j = t - 96;
    float e = mb2[j];
#pragma unroll
    for (int k = 0; k < 32; ++k) e = fmaf(hbuf[k], mw2[k * 16 + j], e);
    invec[t] = e;
  }
  __syncthreads();

  if (t < 128) {
    float a = matb[t];
#pragma unroll 16
    for (int k = 0; k < 112; ++k) a = fmaf(invec[k], matw[k * 128 + t], a);
    zbuf[t] = fmaxf(a, 0.f);
  } else {
    const int c = t - 128;
    float s = schb[c];
#pragma unroll 16
    for (int k = 0; k < 128; ++k)
      s = fmaf(sched[b * 128 + k], schw[k * 128 + c], s);
    zbuf[128 + c] = fmaxf(s, 0.f);
  }
  __syncthreads();

  {
    const int col = t & 127, kh = t >> 7;
    float a = 0.f;
#pragma unroll 16
    for (int kk = 0; kk < 128; ++kk) {
      const int k = kh * 128 + kk;
      a = fmaf(zbuf[k], f1w[k * 128 + col], a);
    }
    psf[t] = a;
  }
  __syncthreads();

  if (t < 128) {
    const float a = psf[t] + psf[128 + t] + f1b[t];
    float v = fmaxf(a, 0.f) * f2w[t];
#pragma unroll
    for (int off = 32; off > 0; off >>= 1) v += __shfl_xor(v, off, 64);
    if ((t & 63) == 0) part[t >> 6] = v;
  }
  __syncthreads();
  if (t == 0) out[b] = part[0] + part[1] + f2b[0];
}

extern "C" void kernel_launch(void* const* d_in, const int* in_sizes, int n_in,
                              void* d_out, int out_size, void* d_ws,
                              size_t ws_size, hipStream_t stream)
{
  (void)in_sizes; (void)n_in; (void)out_size; (void)ws_size;
  const float* x      = (const float*)d_in[0];
  const int*   mask   = (const int*)  d_in[1];
  const float* meta   = (const float*)d_in[2];
  const float* sched  = (const float*)d_in[3];
  const float* w_stem = (const float*)d_in[4];
  const float* w_stg  = (const float*)d_in[5];
  const float* mw1    = (const float*)d_in[6];
  const float* mb1    = (const float*)d_in[7];
  const float* mw2    = (const float*)d_in[8];
  const float* mb2    = (const float*)d_in[9];
  const float* matw   = (const float*)d_in[10];
  const float* matb   = (const float*)d_in[11];
  const float* schw   = (const float*)d_in[12];
  const float* schb   = (const float*)d_in[13];
  const float* f1w    = (const float*)d_in[14];
  const float* f1b    = (const float*)d_in[15];
  const float* f2w    = (const float*)d_in[16];
  const float* f2b    = (const float*)d_in[17];
  float* out = (float*)d_out;

  char* ws = (char*)d_ws;
  size_t off = 0;
  auto alloc = [&](size_t nbytes) -> void* {
    void* p = ws + off;
    off += (nbytes + 255) & ~(size_t)255;
    return p;
  };

  u16* y0 = (u16*)alloc((size_t)NB * 64 * 64 * 64 * CH * 2);
  u16* y1 = (u16*)alloc((size_t)NB * 32 * 32 * 32 * CH * 2);
  u16* y2 = (u16*)alloc((size_t)NB * 16 * 16 * 16 * CH * 2);
  u16* y3 = (u16*)alloc((size_t)NB * 8 * 8 * 8 * CH * 2);
  u8* m1 = (u8*)alloc((size_t)NB * 32 * 32 * 32);
  u8* m2 = (u8*)alloc((size_t)NB * 16 * 16 * 16);
  u8* m3 = (u8*)alloc((size_t)NB * 8 * 8 * 8);
  float* pool_sum = (float*)alloc((NB * 96 + NB * 6) * 4);
  float* cnt = pool_sum + NB * 96;
  u16* bpre = (u16*)alloc((4 * 7168 + 3584) * 2);

  bprep_kernel<<<126, 256, 0, stream>>>(w_stg, w_stem, bpre);

  stem_mfma<<<dim3(512, NB), 256, 0, stream>>>(x, mask, bpre, y0,
                                               pool_sum, cnt);

  // stage 0: 64->32 (32768 vox / 256 = 128 blocks/batch)
  stage_mfma4<64><<<dim3(128, NB), 256, 0, stream>>>(
      y0, bpre + 0 * 7168, mask, (const u8*)nullptr, y1, m1,
      pool_sum, cnt, 0);
  // stage 1: 32->16 (16 blocks/batch)
  stage_mfma4<32><<<dim3(16, NB), 256, 0, stream>>>(
      y1, bpre + 1 * 7168, (const int*)nullptr, m1, y2, m2,
      pool_sum, cnt, 1);
  // stage 2: 16->8 (2 blocks/batch)
  stage_mfma4<16><<<dim3(2, NB), 256, 0, stream>>>(
      y2, bpre + 2 * 7168, (const int*)nullptr, m2, y3, m3,
      pool_sum, cnt, 2);

  tail_kernel<<<NB, 256, 0, stream>>>(y3, m3, bpre, w_stg, meta, sched,
                                      mw1, mb1, mw2, mb2, matw, matb,
                                      schw, schb, f1w, f1b, f2w, f2b,
                                      pool_sum, cnt, out);
}

// Round 8
// 190.323 us; speedup vs baseline: 1.1030x; 1.0226x over previous
//
#include <hip/hip_runtime.h>

#define CH 16
#define NB 8

typedef unsigned short u16;
typedef unsigned char u8;
typedef unsigned int u32;
typedef __attribute__((ext_vector_type(8))) short s16x8;
typedef __attribute__((ext_vector_type(4))) float f32x4;

__device__ __forceinline__ float bflo(u32 u) { return __uint_as_float(u << 16); }
__device__ __forceinline__ float bfhi(u32 u) { return __uint_as_float(u & 0xffff0000u); }
__device__ __forceinline__ u32 bfrnd(float f) {
  u32 u = __float_as_uint(f);
  return (u + 0x7fffu + ((u >> 16) & 1u)) >> 16;
}
// HW packed f32->bf16 RNE convert: 1 VALU inst, bit-identical to bfrnd for
// finite inputs.
__device__ __forceinline__ u32 packbf_hw(float lo, float hi) {
  u32 r;
  asm("v_cvt_pk_bf16_f32 %0, %1, %2" : "=v"(r) : "v"(lo), "v"(hi));
  return r;
}

// ---- Prep: bf16 B-fragments for MFMA stages 0..3 + stem A-fragments -------
// bpre layout: [0 .. 4*7168)  : stage 0..3 B-fragments
//              [4*7168 .. +3584): stem weight fragments [i=0..6][lane][j]
__global__ __launch_bounds__(256) void bprep_kernel(
    const float* __restrict__ w_stg, const float* __restrict__ w_stem,
    u16* __restrict__ bpre)
{
  const int e = blockIdx.x * 256 + (int)threadIdx.x;
  if (e >= 4 * 7168 + 3584) return;
  if (e < 4 * 7168) {
    const int s = e / 7168, r0 = e % 7168;
    const int i = r0 >> 9;
    const int r = r0 & 511;
    const int l = r >> 3, j = r & 7;
    const int tap = 2 * i + (l >> 5);
    const int cin = ((l >> 4) & 1) * 8 + j;
    const int n = l & 15;
    const float* w = w_stg + s * 27 * 256;
    const float val = (tap < 27) ? w[(tap * 16 + cin) * 16 + n] : 0.f;
    bpre[s * 7168 + i * 512 + l * 8 + j] = (u16)bfrnd(val);
  } else {
    const int e2 = e - 4 * 7168;          // [i][lane][j]
    const int i = e2 >> 9;
    const int r0 = e2 & 511;
    const int lane = r0 >> 3, j = r0 & 7;
    const int quad = lane >> 4, n = lane & 15;
    const int r = i * 4 + quad;
    const float val = (r < 25 && j < 5) ? w_stem[(r * 5 + j) * 16 + n] : 0.f;
    bpre[4 * 7168 + e2] = (u16)bfrnd(val);
  }
}

// ---- Stem via MFMA implicit GEMM: merged row-load + copy-build ------------
__global__ __launch_bounds__(256, 6) void stem_mfma(
    const float* __restrict__ x, const int* __restrict__ mask,
    const u16* __restrict__ bpre, u16* __restrict__ yout,
    float* __restrict__ pool_sum, float* __restrict__ cnt)
{
  __shared__ u16 cp[8 * 1168];      // 8 shifted copies, stride 1168 u16

  const int b = blockIdx.y;
  const int u = blockIdx.x;
  const int tb = ((u & 7) << 6) | (u >> 3);   // XCD swizzle: xcd owns z-slab
  const int z0 = (tb >> 6) * 8;
  const int y0 = ((tb >> 3) & 7) * 8;
  const int x0 = (tb & 7) * 8;
  const int tid = threadIdx.x;

  if (tb == 0) {
    if (tid < 96) pool_sum[b * 96 + tid] = 0.f;
    else if (tid < 102) cnt[b * 6 + (tid - 96)] = 0.f;
  }

  const int lane = tid & 63;
  const int wv = tid >> 6;
  const int n = lane & 15;
  const int quad = lane >> 4;
  const int vy = n >> 2, vx = n & 3;

  s16x8 wf[7];
  {
    const s16x8* wfp = (const s16x8*)(bpre + 4 * 7168);
#pragma unroll
    for (int i = 0; i < 7; ++i) wf[i] = wfp[i * 64 + lane];
  }

  if (tid < 144) {
    const int lz = tid / 12, ly = tid - lz * 12;
    const int gz = z0 + lz - 2, gy = y0 + ly - 2;
    uint4* dst = (uint4*)&cp[tid * 8];
    if ((unsigned)gz < 64u && (unsigned)gy < 64u) {
      const long long rowg =
          ((long long)((b * 64 + gz) * 64 + gy)) * 64 + (x0 - 2);
      float v[12];
      if (rowg >= 0 && rowg + 12 <= (long long)NB * 64 * 64 * 64) {
        const float2* xp = (const float2*)(x + rowg);
        const int2* mp2 = (const int2*)(mask + rowg);
        float2 xv[6]; int2 mv2[6];
#pragma unroll
        for (int j = 0; j < 6; ++j) { xv[j] = xp[j]; mv2[j] = mp2[j]; }
#pragma unroll
        for (int j = 0; j < 6; ++j) {
          v[2 * j]     = xv[j].x * (float)mv2[j].x;
          v[2 * j + 1] = xv[j].y * (float)mv2[j].y;
        }
        if (x0 == 0)  { v[0] = 0.f;  v[1] = 0.f;  }
        if (x0 == 56) { v[10] = 0.f; v[11] = 0.f; }
      } else {
#pragma unroll
        for (int j = 0; j < 12; ++j) {
          const int gx = x0 - 2 + j;
          float vv = 0.f;
          if ((unsigned)gx < 64u) {
            const long long gi = rowg + j;
            vv = x[gi] * (float)mask[gi];
          }
          v[j] = vv;
        }
      }
      const u32 c0 = packbf_hw(v[0], v[1]);
      const u32 c1 = packbf_hw(v[2], v[3]);
      const u32 c2 = packbf_hw(v[4], v[5]);
      const u32 c3 = packbf_hw(v[6], v[7]);
      const u32 c4 = packbf_hw(v[8], v[9]);
      const u32 c5 = packbf_hw(v[10], v[11]);
      const u32 d0 = packbf_hw(v[1], v[2]);
      const u32 d1 = packbf_hw(v[3], v[4]);
      const u32 d2 = packbf_hw(v[5], v[6]);
      const u32 d3 = packbf_hw(v[7], v[8]);
      const u32 d4 = packbf_hw(v[9], v[10]);
      const u32 d5 = packbf_hw(v[11], 0.f);
      dst[0 * 146] = make_uint4(c0, c1, c2, c3);
      dst[1 * 146] = make_uint4(d0, d1, d2, d3);
      dst[2 * 146] = make_uint4(c1, c2, c3, c4);
      dst[3 * 146] = make_uint4(d1, d2, d3, d4);
      dst[4 * 146] = make_uint4(c2, c3, c4, c5);
      dst[5 * 146] = make_uint4(d2, d3, d4, d5);
      dst[6 * 146] = make_uint4(c3, c4, c5, 0u);
      dst[7 * 146] = make_uint4(d3, d4, d5, 0u);
    } else {
#pragma unroll
      for (int p = 0; p < 8; ++p) dst[p * 146] = make_uint4(0u, 0u, 0u, 0u);
    }
  }
  __syncthreads();

  int doff[7];
#pragma unroll
  for (int i = 0; i < 7; ++i) {
    const int r = i * 4 + quad;
    doff[i] = (r < 25) ? ((r / 5) * 12 + (r % 5)) * 8 : 0;
  }
  const int base0 = vx * 1168 + (wv * 12 + vy) * 8;
  const int gi0 = ((b * 64 + z0 + wv) * 64 + y0 + vy) * 64 + x0 + vx;
  u16* outp = yout + (size_t)gi0 * 16 + quad * 4;

  float mvc = (float)mask[gi0];
#pragma unroll 2
  for (int s = 0; s < 8; ++s) {
    const int sz = (s >> 2) * 4, sy2 = ((s >> 1) & 1) * 4, sx = (s & 1) * 4;
    const int off = sz * 4096 + sy2 * 64 + sx;
    float mvn = 0.f;
    if (s < 7) {
      const int s1 = s + 1;
      const int offn = ((s1 >> 2) * 4) * 4096 + (((s1 >> 1) & 1) * 4) * 64 +
                       (s1 & 1) * 4;
      mvn = (float)mask[gi0 + offn];
    }
    const int base = base0 + sx * 1168 + (sz * 12 + sy2) * 8;
    f32x4 accA = {0.f, 0.f, 0.f, 0.f};
    f32x4 accB = {0.f, 0.f, 0.f, 0.f};
#pragma unroll
    for (int i = 0; i < 7; ++i) {
      const s16x8 bf = *(const s16x8*)&cp[base + doff[i]];
      if (i & 1)
        accB = __builtin_amdgcn_mfma_f32_16x16x32_bf16(wf[i], bf, accB, 0, 0, 0);
      else
        accA = __builtin_amdgcn_mfma_f32_16x16x32_bf16(wf[i], bf, accA, 0, 0, 0);
    }
    const float f0 = fmaxf(accA[0] + accB[0], 0.f) * mvc;
    const float f1 = fmaxf(accA[1] + accB[1], 0.f) * mvc;
    const float f2 = fmaxf(accA[2] + accB[2], 0.f) * mvc;
    const float f3 = fmaxf(accA[3] + accB[3], 0.f) * mvc;
    *(uint2*)(outp + (size_t)off * 16) =
        make_uint2(packbf_hw(f0, f1), packbf_hw(f2, f3));
    mvc = mvn;
  }
}

// ---- Stages 0..1: MFMA implicit GEMM, swapped operands ---------------------
template <int S>
__global__ __launch_bounds__(256) void stage_mfma4(
    const u16* __restrict__ yin, const u16* __restrict__ bpre,
    const int* __restrict__ m_in_i, const u8* __restrict__ m_in_u8,
    u16* __restrict__ yout, u8* __restrict__ m_out,
    float* __restrict__ pool_sum, float* __restrict__ cnt,
    const int stage)
{
  __shared__ u16 lb[14 * 512];
  __shared__ float lmp[256];
  __shared__ float lps[4][16];

  constexpr int So = S >> 1;
  constexpr int nvox = So * So * So;
  constexpr int NBX = nvox / 256;
  const int b = blockIdx.y;
  const int tid = threadIdx.x;
  const int u = blockIdx.x;
  int bxi;
  if constexpr (NBX >= 8) bxi = (u & 7) * (NBX / 8) + (u >> 3);
  else bxi = u;
  const int vg0 = bxi * 256;

  {
    const uint4* src = (const uint4*)bpre;
    uint4* dst = (uint4*)lb;
    for (int e = tid; e < 896; e += 256) dst[e] = src[e];
  }

  {
    const int vox = vg0 + tid;
    const int oz = vox / (So * So);
    const int oy = (vox / So) % So;
    const int ox = vox % So;
    float mp = 0.f;
#pragma unroll
    for (int dz = 0; dz < 2; ++dz)
#pragma unroll
      for (int dy = 0; dy < 2; ++dy)
#pragma unroll
        for (int dx = 0; dx < 2; ++dx) {
          const int mi =
              ((b * S + 2 * oz + dz) * S + 2 * oy + dy) * S + 2 * ox + dx;
          const float mv = m_in_i ? (float)m_in_i[mi] : (float)m_in_u8[mi];
          mp = fmaxf(mp, mv);
        }
    lmp[tid] = mp;
  }
  __syncthreads();

  const int wv = tid >> 6;
  const int lane = tid & 63;
  const int m = lane & 15;
  const int quad = lane >> 4;
  const int qh = quad >> 1;
  const int qlo = quad & 1;

  int izb[4], iyb[4], ixb[4];
#pragma unroll
  for (int g = 0; g < 4; ++g) {
    const int vox = vg0 + wv * 64 + g * 16 + m;
    const int oz = vox / (So * So);
    const int oy = (vox / So) % So;
    const int ox = vox % So;
    izb[g] = 2 * oz - 1;
    iyb[g] = 2 * oy - 1;
    ixb[g] = 2 * ox - 1;
  }

  const s16x8* lbv = (const s16x8*)lb;
  f32x4 acc[4];
#pragma unroll
  for (int g = 0; g < 4; ++g) acc[g] = (f32x4){0.f, 0.f, 0.f, 0.f};

#pragma unroll
  for (int i = 0; i < 14; ++i) {
    const int t0 = 2 * i, t1 = 2 * i + 1;
    const int dz0 = t0 / 9, dy0 = (t0 / 3) % 3, dx0 = t0 % 3;
    const int dz1 = (t1 < 27) ? t1 / 9 : 1;
    const int dy1 = (t1 < 27) ? (t1 / 3) % 3 : 1;
    const int dx1 = (t1 < 27) ? t1 % 3 : 1;
    const int dzq = qh ? dz1 : dz0;
    const int dyq = qh ? dy1 : dy0;
    const int dxq = qh ? dx1 : dx0;

    uint4 ar[4];
#pragma unroll
    for (int g = 0; g < 4; ++g) {
      const int iz = izb[g] + dzq;
      const int iy = iyb[g] + dyq;
      const int ix = ixb[g] + dxq;
      const bool valid = (unsigned)iz < (unsigned)S &&
                         (unsigned)iy < (unsigned)S &&
                         (unsigned)ix < (unsigned)S;
      const int izc = min(max(iz, 0), S - 1);
      const int iyc = min(max(iy, 0), S - 1);
      const int ixc = min(max(ix, 0), S - 1);
      const size_t addr =
          (size_t)(((b * S + izc) * S + iyc) * S + ixc) * 16 + qlo * 8;
      uint4 v = *(const uint4*)(yin + addr);
      v.x = valid ? v.x : 0u;
      v.y = valid ? v.y : 0u;
      v.z = valid ? v.z : 0u;
      v.w = valid ? v.w : 0u;
      ar[g] = v;
    }
    const s16x8 bfrag = lbv[i * 64 + lane];
#pragma unroll
    for (int g = 0; g < 4; ++g)
      acc[g] = __builtin_amdgcn_mfma_f32_16x16x32_bf16(
          bfrag, __builtin_bit_cast(s16x8, ar[g]), acc[g], 0, 0, 0);
  }

  {
    float ps0 = 0.f, ps1 = 0.f, ps2 = 0.f, ps3 = 0.f;
#pragma unroll
    for (int g = 0; g < 4; ++g) {
      const int lv = wv * 64 + g * 16 + m;
      const float mp = lmp[lv];
      const float f0 = fmaxf(acc[g][0], 0.f) * mp;
      const float f1 = fmaxf(acc[g][1], 0.f) * mp;
      const float f2 = fmaxf(acc[g][2], 0.f) * mp;
      const float f3 = fmaxf(acc[g][3], 0.f) * mp;
      const size_t gi = (size_t)b * nvox + vg0 + lv;
      *(uint2*)(yout + gi * 16 + quad * 4) =
          make_uint2(packbf_hw(f0, f1), packbf_hw(f2, f3));
      if (quad == 0) m_out[gi] = (u8)mp;
      ps0 += f0; ps1 += f1; ps2 += f2; ps3 += f3;
    }
#pragma unroll
    for (int mm = 1; mm < 16; mm <<= 1) {
      ps0 += __shfl_xor(ps0, mm, 64);
      ps1 += __shfl_xor(ps1, mm, 64);
      ps2 += __shfl_xor(ps2, mm, 64);
      ps3 += __shfl_xor(ps3, mm, 64);
    }
    if (m == 0) {
      lps[wv][quad * 4 + 0] = ps0;
      lps[wv][quad * 4 + 1] = ps1;
      lps[wv][quad * 4 + 2] = ps2;
      lps[wv][quad * 4 + 3] = ps3;
    }
  }
  __syncthreads();
  if (tid < 16) {
    const float s = lps[0][tid] + lps[1][tid] + lps[2][tid] + lps[3][tid];
    atomicAdd(&pool_sum[(b * 6 + stage) * 16 + tid], s);
  } else if (tid == 16) {
    float c = 0.f;
#pragma unroll 16
    for (int v = 0; v < 256; ++v) c += lmp[v];
    atomicAdd(&cnt[b * 6 + stage], c);
  }
}

// --------- Tail: stage 2 fused (swapped-operand MFMA, y3 kept in LDS) +
// stage 3 MFMA (K split over 4 waves) + stages 4/5 split-K VALU + MLP head.
// One block per batch; reads y2/m2 directly (L2-hot). ----------------------
__global__ __launch_bounds__(256) void tail_kernel(
    const u16* __restrict__ y2g, const u8* __restrict__ m2g,
    const u16* __restrict__ bpre,
    const float* __restrict__ wstg,
    const float* __restrict__ meta, const float* __restrict__ sched,
    const float* __restrict__ mw1, const float* __restrict__ mb1,
    const float* __restrict__ mw2, const float* __restrict__ mb2,
    const float* __restrict__ matw, const float* __restrict__ matb,
    const float* __restrict__ schw, const float* __restrict__ schb,
    const float* __restrict__ f1w, const float* __restrict__ f1b,
    const float* __restrict__ f2w, const float* __restrict__ f2b,
    const float* __restrict__ pool_sum, const float* __restrict__ cnt,
    float* __restrict__ out)
{
  const int b = blockIdx.x;
  const int t = threadIdx.x;
  __shared__ u16 ty3[8192];           // y3 in bf16 (built in-LDS by stage 2)
  __shared__ float lm3[512];
  __shared__ float pb[4 * 64 * 17];   // stage-3 wave partials (pad 17)
  __shared__ float ly4[64 * 16];
  __shared__ float lm4[64];
  __shared__ float ps4[256];
  __shared__ float ly5[8 * 16];
  __shared__ float lm5[8];
  __shared__ float ps5[128];
  __shared__ float lsum[4][16];       // stage 2,3,4,5 pool sums
  __shared__ float lcnt[4];
  __shared__ float lps2[4][16];
  __shared__ float lcw[4];
  __shared__ float invec[112];
  __shared__ float hbuf[32];
  __shared__ float zbuf[256];
  __shared__ float psf[256];
  __shared__ float part[2];

  const int lane = t & 63;
  const int wv = t >> 6;
  const int mm = lane & 15;
  const int quad = lane >> 4;
  const int qh = quad >> 1, qlo = quad & 1;

  // ---- P0: stage 2 (16->8), swapped operands, output straight into LDS ----
  {
    const s16x8* bp2 = (const s16x8*)(bpre + 2 * 7168);
    float ps0 = 0.f, ps1 = 0.f, ps2 = 0.f, ps3 = 0.f;
    float cmask = 0.f;
#pragma unroll
    for (int p = 0; p < 2; ++p) {
      const int vg0 = p * 256;
      {
        const int vox = vg0 + t;
        const int oz = vox >> 6, oy = (vox >> 3) & 7, ox = vox & 7;
        float mp = 0.f;
#pragma unroll
        for (int dz = 0; dz < 2; ++dz)
#pragma unroll
          for (int dy = 0; dy < 2; ++dy)
#pragma unroll
            for (int dx = 0; dx < 2; ++dx)
              mp = fmaxf(mp, (float)m2g[((b * 16 + 2 * oz + dz) * 16 +
                                         2 * oy + dy) * 16 + 2 * ox + dx]);
        lm3[vox] = mp;
        cmask += mp;
      }
      int izb[4], iyb[4], ixb[4];
#pragma unroll
      for (int g = 0; g < 4; ++g) {
        const int vox = vg0 + wv * 64 + g * 16 + mm;
        izb[g] = 2 * (vox >> 6) - 1;
        iyb[g] = 2 * ((vox >> 3) & 7) - 1;
        ixb[g] = 2 * (vox & 7) - 1;
      }
      f32x4 acc[4];
#pragma unroll
      for (int g = 0; g < 4; ++g) acc[g] = (f32x4){0.f, 0.f, 0.f, 0.f};
#pragma unroll
      for (int i = 0; i < 14; ++i) {
        const int t0 = 2 * i, t1 = 2 * i + 1;
        const int dz0 = t0 / 9, dy0 = (t0 / 3) % 3, dx0 = t0 % 3;
        const int dz1 = (t1 < 27) ? t1 / 9 : 1;
        const int dy1 = (t1 < 27) ? (t1 / 3) % 3 : 1;
        const int dx1 = (t1 < 27) ? t1 % 3 : 1;
        const int dzq = qh ? dz1 : dz0;
        const int dyq = qh ? dy1 : dy0;
        const int dxq = qh ? dx1 : dx0;
        uint4 ar[4];
#pragma unroll
        for (int g = 0; g < 4; ++g) {
          const int iz = izb[g] + dzq;
          const int iy = iyb[g] + dyq;
          const int ix = ixb[g] + dxq;
          const bool valid = (unsigned)iz < 16u && (unsigned)iy < 16u &&
                             (unsigned)ix < 16u;
          const int izc = min(max(iz, 0), 15);
          const int iyc = min(max(iy, 0), 15);
          const int ixc = min(max(ix, 0), 15);
          const size_t addr =
              (size_t)(((b * 16 + izc) * 16 + iyc) * 16 + ixc) * 16 + qlo * 8;
          uint4 v = *(const uint4*)(y2g + addr);
          v.x = valid ? v.x : 0u;
          v.y = valid ? v.y : 0u;
          v.z = valid ? v.z : 0u;
          v.w = valid ? v.w : 0u;
          ar[g] = v;
        }
        const s16x8 bfrag = bp2[i * 64 + lane];
#pragma unroll
        for (int g = 0; g < 4; ++g)
          acc[g] = __builtin_amdgcn_mfma_f32_16x16x32_bf16(
              bfrag, __builtin_bit_cast(s16x8, ar[g]), acc[g], 0, 0, 0);
      }
      __syncthreads();                 // lm3 of this pass visible
#pragma unroll
      for (int g = 0; g < 4; ++g) {
        const int lv = vg0 + wv * 64 + g * 16 + mm;
        const float mp = lm3[lv];
        const float f0 = fmaxf(acc[g][0], 0.f) * mp;
        const float f1 = fmaxf(acc[g][1], 0.f) * mp;
        const float f2 = fmaxf(acc[g][2], 0.f) * mp;
        const float f3 = fmaxf(acc[g][3], 0.f) * mp;
        *(uint2*)&ty3[lv * 16 + quad * 4] =
            make_uint2(packbf_hw(f0, f1), packbf_hw(f2, f3));
        ps0 += f0; ps1 += f1; ps2 += f2; ps3 += f3;
      }
    }
    // channel pool sums over both passes
#pragma unroll
    for (int s = 1; s < 16; s <<= 1) {
      ps0 += __shfl_xor(ps0, s, 64);
      ps1 += __shfl_xor(ps1, s, 64);
      ps2 += __shfl_xor(ps2, s, 64);
      ps3 += __shfl_xor(ps3, s, 64);
    }
    if (mm == 0) {
      lps2[wv][quad * 4 + 0] = ps0;
      lps2[wv][quad * 4 + 1] = ps1;
      lps2[wv][quad * 4 + 2] = ps2;
      lps2[wv][quad * 4 + 3] = ps3;
    }
    // mask count (each thread owns lm3[t] and lm3[256+t])
#pragma unroll
    for (int s = 1; s < 64; s <<= 1) cmask += __shfl_xor(cmask, s, 64);
    if (lane == 0) lcw[wv] = cmask;
  }
  __syncthreads();
  if (t < 16) {
    lsum[0][t] = lps2[0][t] + lps2[1][t] + lps2[2][t] + lps2[3][t];
  } else if (t == 16) {
    lcnt[0] = lcw[0] + lcw[1] + lcw[2] + lcw[3];
  }

  // ---- P1: stage 3 MFMA, tap-pairs split across waves (reads ty3/LDS) ----
  {
    int iz0[4], iy0[4], ix0[4];
#pragma unroll
    for (int g = 0; g < 4; ++g) {
      const int vox = g * 16 + mm;
      iz0[g] = 2 * (vox >> 4) - 1;
      iy0[g] = 2 * ((vox >> 2) & 3) - 1;
      ix0[g] = 2 * (vox & 3) - 1;
    }
    f32x4 a3[4];
#pragma unroll
    for (int g = 0; g < 4; ++g) a3[g] = (f32x4){0.f, 0.f, 0.f, 0.f};
    const s16x8* bp3 = (const s16x8*)(bpre + 3 * 7168);
#pragma unroll
    for (int ii = 0; ii < 4; ++ii) {
      const int i = wv * 4 + ii;
      if (i < 14) {
        const int t0 = 2 * i, t1 = 2 * i + 1;
        const int dz0 = t0 / 9, dy0 = (t0 / 3) % 3, dx0 = t0 % 3;
        const int dz1 = (t1 < 27) ? t1 / 9 : 1;
        const int dy1 = (t1 < 27) ? (t1 / 3) % 3 : 1;
        const int dx1 = (t1 < 27) ? t1 % 3 : 1;
        const int dzq = qh ? dz1 : dz0;
        const int dyq = qh ? dy1 : dy0;
        const int dxq = qh ? dx1 : dx0;
        uint4 ar[4];
#pragma unroll
        for (int g = 0; g < 4; ++g) {
          const int iz = iz0[g] + dzq;
          const int iy = iy0[g] + dyq;
          const int ix = ix0[g] + dxq;
          const bool valid = (unsigned)iz < 8u && (unsigned)iy < 8u &&
                             (unsigned)ix < 8u;
          const int izc = min(max(iz, 0), 7);
          const int iyc = min(max(iy, 0), 7);
          const int ixc = min(max(ix, 0), 7);
          const int ad = ((izc * 8 + iyc) * 8 + ixc) * 16 + qlo * 8;
          uint4 v = *(const uint4*)&ty3[ad];
          v.x = valid ? v.x : 0u;
          v.y = valid ? v.y : 0u;
          v.z = valid ? v.z : 0u;
          v.w = valid ? v.w : 0u;
          ar[g] = v;
        }
        const s16x8 bf = bp3[i * 64 + lane];
#pragma unroll
        for (int g = 0; g < 4; ++g)
          a3[g] = __builtin_amdgcn_mfma_f32_16x16x32_bf16(
              __builtin_bit_cast(s16x8, ar[g]), bf, a3[g], 0, 0, 0);
      }
    }
#pragma unroll
    for (int g = 0; g < 4; ++g)
#pragma unroll
      for (int reg = 0; reg < 4; ++reg)
        pb[wv * 1088 + (g * 16 + quad * 4 + reg) * 17 + mm] = a3[g][reg];
  }
  __syncthreads();

  // ---- P2: reduce 4 wave-partials -> relu * mask -> ly4 (f32)
  {
    const int vox = t >> 2, cg = (t & 3) * 4;
    const int oz = vox >> 4, oy = (vox >> 2) & 3, ox = vox & 3;
    float mp = 0.f;
#pragma unroll
    for (int dz = 0; dz < 2; ++dz)
#pragma unroll
      for (int dy = 0; dy < 2; ++dy)
#pragma unroll
        for (int dx = 0; dx < 2; ++dx)
          mp = fmaxf(mp, lm3[((2 * oz + dz) * 8 + 2 * oy + dy) * 8 +
                             2 * ox + dx]);
#pragma unroll
    for (int c = 0; c < 4; ++c) {
      const int ch = cg + c;
      const float s = pb[vox * 17 + ch] + pb[1088 + vox * 17 + ch] +
                      pb[2176 + vox * 17 + ch] + pb[3264 + vox * 17 + ch];
      ly4[vox * 16 + ch] = fmaxf(s, 0.f) * mp;
    }
    if (cg == 0) lm4[vox] = mp;
  }
  __syncthreads();

  // ---- P3: stage-3 pools + stage 4 split-K (all 256 threads)
  if (t < 16) {
    float s = 0.f;
#pragma unroll 16
    for (int v = 0; v < 64; ++v) s += ly4[v * 16 + t];
    lsum[1][t] = s;
  } else if (t == 16) {
    float s = 0.f;
#pragma unroll 16
    for (int v = 0; v < 64; ++v) s += lm4[v];
    lcnt[1] = s;
  }
  {
    const float* w = wstg + 4 * 27 * 256;
    const int o = t >> 1, kh = t & 1;
    const int vox4 = o >> 4, co = o & 15;
    const int oz = vox4 >> 2, oy = (vox4 >> 1) & 1, ox = vox4 & 1;
    float acc = 0.f;
#pragma unroll
    for (int tt = 0; tt < 14; ++tt) {
      const int tap = tt + (kh ? 14 : 0);
      if (tap < 27) {
        const int dz = tap / 9, dy = (tap / 3) % 3, dx = tap % 3;
        const int iz = 2 * oz + dz - 1, iy = 2 * oy + dy - 1,
                  ix = 2 * ox + dx - 1;
        const float s = ((unsigned)iz < 4u && (unsigned)iy < 4u &&
                         (unsigned)ix < 4u) ? 1.f : 0.f;
        const int idx = ((min(max(iz, 0), 3) * 4 + min(max(iy, 0), 3)) * 4 +
                         min(max(ix, 0), 3)) * 16;
        const float* wp = w + tap * 256 + co;
#pragma unroll
        for (int ci = 0; ci < 16; ++ci)
          acc = fmaf(ly4[idx + ci] * s, wp[ci * 16], acc);
      }
    }
    ps4[t] = acc;
  }
  __syncthreads();

  // ---- P4: combine stage-4 partials -> ly5
  if (t < 128) {
    const int vox4 = t >> 4, co = t & 15;
    float mp = 0.f;
#pragma unroll
    for (int dz = 0; dz < 2; ++dz)
#pragma unroll
      for (int dy = 0; dy < 2; ++dy)
#pragma unroll
        for (int dx = 0; dx < 2; ++dx)
          mp = fmaxf(mp, lm4[((2 * (vox4 >> 2) + dz) * 4 +
                              2 * ((vox4 >> 1) & 1) + dy) * 4 +
                             2 * (vox4 & 1) + dx]);
    ly5[t] = fmaxf(ps4[2 * t] + ps4[2 * t + 1], 0.f) * mp;
    if (co == 0) lm5[vox4] = mp;
  }
  __syncthreads();

  // ---- P5: stage-4 pools + stage 5 split-K (128 threads, 8 K-slices)
  if (t < 16) {
    float s = 0.f;
#pragma unroll
    for (int v = 0; v < 8; ++v) s += ly5[v * 16 + t];
    lsum[2][t] = s;
  } else if (t == 16) {
    lcnt[2] = lm5[0] + lm5[1] + lm5[2] + lm5[3] + lm5[4] + lm5[5] + lm5[6] +
              lm5[7];
  }
  if (t < 128) {
    const float* w = wstg + 5 * 27 * 256;
    const int co = t & 15, k8 = t >> 4;
    float acc = 0.f;
#pragma unroll
    for (int tt = 0; tt < 4; ++tt) {
      const int tap = k8 * 4 + tt;
      if (tap < 27) {
        const int dz = tap / 9, dy = (tap / 3) % 3, dx = tap % 3;
        const int iz = dz - 1, iy = dy - 1, ix = dx - 1;
        const float s = ((unsigned)iz < 2u && (unsigned)iy < 2u &&
                         (unsigned)ix < 2u) ? 1.f : 0.f;
        const int idx = ((min(max(iz, 0), 1) * 2 + min(max(iy, 0), 1)) * 2 +
                         min(max(ix, 0), 1)) * 16;
        const float* wp = w + tap * 256 + co;
#pragma unroll
        for (int ci = 0; ci < 16; ++ci)
          acc = fmaf(ly5[idx + ci] * s, wp[ci * 16], acc);
      }
    }
    ps5[t] = acc;
  }
  __syncthreads();

  // ---- P6: combine stage-5 partials; meta layer 1
  if (t < 16) {
    float s = ps5[t] + ps5[16 + t] + ps5[32 + t] + ps5[48 + t] +
              ps5[64 + t] + ps5[80 + t] + ps5[96 + t] + ps5[112 + t];
    float mp = 0.f;
#pragma unroll
    for (int v = 0; v < 8; ++v) mp = fmaxf(mp, lm5[v]);
    lsum[3][t] = fmaxf(s, 0.f) * mp;
    if (t == 0) lcnt[3] = mp;
  } else if (t >= 96 && t < 128) {
    const int j = t - 96;
    float h = mb1[j];
#pragma unroll
    for (int k = 0; k < 3; ++k) h = fmaf(meta[b * 3 + k], mw1[k * 32 + j], h);
    hbuf[j] = fmaxf(h, 0.f);
  }
  __syncthreads();

  // ---- P7: build invec (stages 0,1 from global; 2..5 local; meta_emb)
  if (t < 32) {
    const int s = t >> 4;
    invec[t] = pool_sum[b * 96 + t] / fmaxf(cnt[b * 6 + s], 1.f);
  } else if (t < 96) {
    const int s = (t >> 4) - 2;
    invec[t] = lsum[s][t & 15] / fmaxf(lcnt[s], 1.f);
  } else if (t < 112) {
    const int j = t - 96;
    float e = mb2[j];
#pragma unroll
    for (int k = 0; k < 32; ++k) e = fmaf(hbuf[k], mw2[k * 16 + j], e);
    invec[t] = e;  // no ReLU on meta_emb
  }
  __syncthreads();

  // ---- P8: zbuf = [relu(invec@matw), relu(sched@schw)] in parallel halves
  if (t < 128) {
    float a = matb[t];
#pragma unroll 16
    for (int k = 0; k < 112; ++k) a = fmaf(invec[k], matw[k * 128 + t], a);
    zbuf[t] = fmaxf(a, 0.f);
  } else {
    const int c = t - 128;
    float s = schb[c];
#pragma unroll 16
    for (int k = 0; k < 128; ++k)
      s = fmaf(sched[b * 128 + k], schw[k * 128 + c], s);
    zbuf[128 + c] = fmaxf(s, 0.f);
  }
  __syncthreads();

  // ---- P9: f1 with K split across thread halves
  {
    const int col = t & 127, kh = t >> 7;
    float a = 0.f;
#pragma unroll 16
    for (int kk = 0; kk < 128; ++kk) {
      const int k = kh * 128 + kk;
      a = fmaf(zbuf[k], f1w[k * 128 + col], a);
    }
    psf[t] = a;
  }
  __syncthreads();

  // ---- P10: final combine + dot with f2w
  if (t < 128) {
    const float a = psf[t] + psf[128 + t] + f1b[t];
    float v = fmaxf(a, 0.f) * f2w[t];
#pragma unroll
    for (int off = 32; off > 0; off >>= 1) v += __shfl_xor(v, off, 64);
    if ((t & 63) == 0) part[t >> 6] = v;
  }
  __syncthreads();
  if (t == 0) out[b] = part[0] + part[1] + f2b[0];
}

extern "C" void kernel_launch(void* const* d_in, const int* in_sizes, int n_in,
                              void* d_out, int out_size, void* d_ws,
                              size_t ws_size, hipStream_t stream)
{
  (void)in_sizes; (void)n_in; (void)out_size; (void)ws_size;
  const float* x      = (const float*)d_in[0];
  const int*   mask   = (const int*)  d_in[1];
  const float* meta   = (const float*)d_in[2];
  const float* sched  = (const float*)d_in[3];
  const float* w_stem = (const float*)d_in[4];
  const float* w_stg  = (const float*)d_in[5];
  const float* mw1    = (const float*)d_in[6];
  const float* mb1    = (const float*)d_in[7];
  const float* mw2    = (const float*)d_in[8];
  const float* mb2    = (const float*)d_in[9];
  const float* matw   = (const float*)d_in[10];
  const float* matb   = (const float*)d_in[11];
  const float* schw   = (const float*)d_in[12];
  const float* schb   = (const float*)d_in[13];
  const float* f1w    = (const float*)d_in[14];
  const float* f1b    = (const float*)d_in[15];
  const float* f2w    = (const float*)d_in[16];
  const float* f2b    = (const float*)d_in[17];
  float* out = (float*)d_out;

  char* ws = (char*)d_ws;
  size_t off = 0;
  auto alloc = [&](size_t nbytes) -> void* {
    void* p = ws + off;
    off += (nbytes + 255) & ~(size_t)255;
    return p;
  };

  u16* y0 = (u16*)alloc((size_t)NB * 64 * 64 * 64 * CH * 2);
  u16* y1 = (u16*)alloc((size_t)NB * 32 * 32 * 32 * CH * 2);
  u16* y2 = (u16*)alloc((size_t)NB * 16 * 16 * 16 * CH * 2);
  u8* m1 = (u8*)alloc((size_t)NB * 32 * 32 * 32);
  u8* m2 = (u8*)alloc((size_t)NB * 16 * 16 * 16);
  float* pool_sum = (float*)alloc((NB * 96 + NB * 6) * 4);
  float* cnt = pool_sum + NB * 96;
  u16* bpre = (u16*)alloc((4 * 7168 + 3584) * 2);

  bprep_kernel<<<126, 256, 0, stream>>>(w_stg, w_stem, bpre);

  stem_mfma<<<dim3(512, NB), 256, 0, stream>>>(x, mask, bpre, y0,
                                               pool_sum, cnt);

  // stage 0: 64->32 (32768 vox / 256 = 128 blocks/batch)
  stage_mfma4<64><<<dim3(128, NB), 256, 0, stream>>>(
      y0, bpre + 0 * 7168, mask, (const u8*)nullptr, y1, m1,
      pool_sum, cnt, 0);
  // stage 1: 32->16 (16 blocks/batch)
  stage_mfma4<32><<<dim3(16, NB), 256, 0, stream>>>(
      y1, bpre + 1 * 7168, (const int*)nullptr, m1, y2, m2,
      pool_sum, cnt, 1);

  // stage 2 fused into tail (reads y2/m2 directly, y3 lives in LDS)
  tail_kernel<<<NB, 256, 0, stream>>>(y2, m2, bpre, w_stg, meta, sched,
                                      mw1, mb1, mw2, mb2, matw, matb,
                                      schw, schb, f1w, f1b, f2w, f2b,
                                      pool_sum, cnt, out);
}

// Round 9
// 182.064 us; speedup vs baseline: 1.1531x; 1.0454x over previous
//
#include <hip/hip_runtime.h>

#define CH 16
#define NB 8

typedef unsigned short u16;
typedef unsigned char u8;
typedef unsigned int u32;
typedef __attribute__((ext_vector_type(8))) short s16x8;
typedef __attribute__((ext_vector_type(4))) float f32x4;

__device__ __forceinline__ float bflo(u32 u) { return __uint_as_float(u << 16); }
__device__ __forceinline__ float bfhi(u32 u) { return __uint_as_float(u & 0xffff0000u); }
__device__ __forceinline__ u32 bfrnd(float f) {
  u32 u = __float_as_uint(f);
  return (u + 0x7fffu + ((u >> 16) & 1u)) >> 16;
}
// HW packed f32->bf16 RNE convert: 1 VALU inst, bit-identical to bfrnd for
// finite inputs.
__device__ __forceinline__ u32 packbf_hw(float lo, float hi) {
  u32 r;
  asm("v_cvt_pk_bf16_f32 %0, %1, %2" : "=v"(r) : "v"(lo), "v"(hi));
  return r;
}

// ---- Prep: bf16 B-fragments for MFMA stages 0..3 + stem A-fragments -------
// bpre layout: [0 .. 4*7168)  : stage 0..3 B-fragments
//              [4*7168 .. +3584): stem weight fragments [i=0..6][lane][j]
__global__ __launch_bounds__(256) void bprep_kernel(
    const float* __restrict__ w_stg, const float* __restrict__ w_stem,
    u16* __restrict__ bpre)
{
  const int e = blockIdx.x * 256 + (int)threadIdx.x;
  if (e >= 4 * 7168 + 3584) return;
  if (e < 4 * 7168) {
    const int s = e / 7168, r0 = e % 7168;
    const int i = r0 >> 9;
    const int r = r0 & 511;
    const int l = r >> 3, j = r & 7;
    const int tap = 2 * i + (l >> 5);
    const int cin = ((l >> 4) & 1) * 8 + j;
    const int n = l & 15;
    const float* w = w_stg + s * 27 * 256;
    const float val = (tap < 27) ? w[(tap * 16 + cin) * 16 + n] : 0.f;
    bpre[s * 7168 + i * 512 + l * 8 + j] = (u16)bfrnd(val);
  } else {
    const int e2 = e - 4 * 7168;          // [i][lane][j]
    const int i = e2 >> 9;
    const int r0 = e2 & 511;
    const int lane = r0 >> 3, j = r0 & 7;
    const int quad = lane >> 4, n = lane & 15;
    const int r = i * 4 + quad;
    const float val = (r < 25 && j < 5) ? w_stem[(r * 5 + j) * 16 + n] : 0.f;
    bpre[4 * 7168 + e2] = (u16)bfrnd(val);
  }
}

// ---- Stem via MFMA implicit GEMM: merged row-load + copy-build ------------
// Inner 8x8x8 mask is packed to LDS (u8) during row staging, so the epilogue
// reads masks from LDS instead of 9 scattered global loads per thread.
__global__ __launch_bounds__(256, 6) void stem_mfma(
    const float* __restrict__ x, const int* __restrict__ mask,
    const u16* __restrict__ bpre, u16* __restrict__ yout,
    float* __restrict__ pool_sum, float* __restrict__ cnt)
{
  __shared__ u16 cp[8 * 1168];      // 8 shifted copies, stride 1168 u16
  __shared__ u8 lmsk[512];          // inner 8x8x8 mask

  const int b = blockIdx.y;
  const int u = blockIdx.x;
  const int tb = ((u & 7) << 6) | (u >> 3);   // XCD swizzle: xcd owns z-slab
  const int z0 = (tb >> 6) * 8;
  const int y0 = ((tb >> 3) & 7) * 8;
  const int x0 = (tb & 7) * 8;
  const int tid = threadIdx.x;

  if (tb == 0) {
    if (tid < 96) pool_sum[b * 96 + tid] = 0.f;
    else if (tid < 102) cnt[b * 6 + (tid - 96)] = 0.f;
  }

  const int lane = tid & 63;
  const int wv = tid >> 6;
  const int n = lane & 15;
  const int quad = lane >> 4;
  const int vy = n >> 2, vx = n & 3;

  s16x8 wf[7];
  {
    const s16x8* wfp = (const s16x8*)(bpre + 4 * 7168);
#pragma unroll
    for (int i = 0; i < 7; ++i) wf[i] = wfp[i * 64 + lane];
  }

  if (tid < 144) {
    const int lz = tid / 12, ly = tid - lz * 12;
    const int gz = z0 + lz - 2, gy = y0 + ly - 2;
    uint4* dst = (uint4*)&cp[tid * 8];
    if ((unsigned)gz < 64u && (unsigned)gy < 64u) {
      const long long rowg =
          ((long long)((b * 64 + gz) * 64 + gy)) * 64 + (x0 - 2);
      float v[12];
      int mk[12];
      if (rowg >= 0 && rowg + 12 <= (long long)NB * 64 * 64 * 64) {
        const float2* xp = (const float2*)(x + rowg);
        const int2* mp2 = (const int2*)(mask + rowg);
        float2 xv[6]; int2 mv2[6];
#pragma unroll
        for (int j = 0; j < 6; ++j) { xv[j] = xp[j]; mv2[j] = mp2[j]; }
#pragma unroll
        for (int j = 0; j < 6; ++j) {
          v[2 * j]     = xv[j].x * (float)mv2[j].x;
          v[2 * j + 1] = xv[j].y * (float)mv2[j].y;
          mk[2 * j]     = mv2[j].x;
          mk[2 * j + 1] = mv2[j].y;
        }
        if (x0 == 0)  { v[0] = 0.f;  v[1] = 0.f;  }
        if (x0 == 56) { v[10] = 0.f; v[11] = 0.f; }
      } else {
#pragma unroll
        for (int j = 0; j < 12; ++j) {
          const int gx = x0 - 2 + j;
          float vv = 0.f;
          int mm = 0;
          if ((unsigned)gx < 64u) {
            const long long gi = rowg + j;
            mm = mask[gi];
            vv = x[gi] * (float)mm;
          }
          v[j] = vv;
          mk[j] = mm;
        }
      }
      // inner-mask pack: rows lz,ly in [2,10) cover the 8x8x8 output region;
      // x offsets j=2..9 are always in-bounds for those rows.
      if ((unsigned)(lz - 2) < 8u && (unsigned)(ly - 2) < 8u) {
        const u32 lo = (u32)(mk[2] & 1) | ((u32)(mk[3] & 1) << 8) |
                       ((u32)(mk[4] & 1) << 16) | ((u32)(mk[5] & 1) << 24);
        const u32 hi = (u32)(mk[6] & 1) | ((u32)(mk[7] & 1) << 8) |
                       ((u32)(mk[8] & 1) << 16) | ((u32)(mk[9] & 1) << 24);
        u32* lp = (u32*)&lmsk[((lz - 2) * 8 + (ly - 2)) * 8];
        lp[0] = lo; lp[1] = hi;
      }
      const u32 c0 = packbf_hw(v[0], v[1]);
      const u32 c1 = packbf_hw(v[2], v[3]);
      const u32 c2 = packbf_hw(v[4], v[5]);
      const u32 c3 = packbf_hw(v[6], v[7]);
      const u32 c4 = packbf_hw(v[8], v[9]);
      const u32 c5 = packbf_hw(v[10], v[11]);
      const u32 d0 = packbf_hw(v[1], v[2]);
      const u32 d1 = packbf_hw(v[3], v[4]);
      const u32 d2 = packbf_hw(v[5], v[6]);
      const u32 d3 = packbf_hw(v[7], v[8]);
      const u32 d4 = packbf_hw(v[9], v[10]);
      const u32 d5 = packbf_hw(v[11], 0.f);
      dst[0 * 146] = make_uint4(c0, c1, c2, c3);
      dst[1 * 146] = make_uint4(d0, d1, d2, d3);
      dst[2 * 146] = make_uint4(c1, c2, c3, c4);
      dst[3 * 146] = make_uint4(d1, d2, d3, d4);
      dst[4 * 146] = make_uint4(c2, c3, c4, c5);
      dst[5 * 146] = make_uint4(d2, d3, d4, d5);
      dst[6 * 146] = make_uint4(c3, c4, c5, 0u);
      dst[7 * 146] = make_uint4(d3, d4, d5, 0u);
    } else {
#pragma unroll
      for (int p = 0; p < 8; ++p) dst[p * 146] = make_uint4(0u, 0u, 0u, 0u);
    }
  }
  __syncthreads();

  int doff[7];
#pragma unroll
  for (int i = 0; i < 7; ++i) {
    const int r = i * 4 + quad;
    doff[i] = (r < 25) ? ((r / 5) * 12 + (r % 5)) * 8 : 0;
  }
  const int base0 = vx * 1168 + (wv * 12 + vy) * 8;
  const int gi0 = ((b * 64 + z0 + wv) * 64 + y0 + vy) * 64 + x0 + vx;
  u16* outp = yout + (size_t)gi0 * 16 + quad * 4;

#pragma unroll 2
  for (int s = 0; s < 8; ++s) {
    const int sz = (s >> 2) * 4, sy2 = ((s >> 1) & 1) * 4, sx = (s & 1) * 4;
    const int off = sz * 4096 + sy2 * 64 + sx;
    const float mvc =
        (float)lmsk[((sz + wv) * 8 + sy2 + vy) * 8 + sx + vx];
    const int base = base0 + sx * 1168 + (sz * 12 + sy2) * 8;
    f32x4 accA = {0.f, 0.f, 0.f, 0.f};
    f32x4 accB = {0.f, 0.f, 0.f, 0.f};
#pragma unroll
    for (int i = 0; i < 7; ++i) {
      const s16x8 bf = *(const s16x8*)&cp[base + doff[i]];
      if (i & 1)
        accB = __builtin_amdgcn_mfma_f32_16x16x32_bf16(wf[i], bf, accB, 0, 0, 0);
      else
        accA = __builtin_amdgcn_mfma_f32_16x16x32_bf16(wf[i], bf, accA, 0, 0, 0);
    }
    const float f0 = fmaxf(accA[0] + accB[0], 0.f) * mvc;
    const float f1 = fmaxf(accA[1] + accB[1], 0.f) * mvc;
    const float f2 = fmaxf(accA[2] + accB[2], 0.f) * mvc;
    const float f3 = fmaxf(accA[3] + accB[3], 0.f) * mvc;
    *(uint2*)(outp + (size_t)off * 16) =
        make_uint2(packbf_hw(f0, f1), packbf_hw(f2, f3));
  }
}

// ---- Stages 0..1: MFMA implicit GEMM, swapped operands ---------------------
template <int S>
__global__ __launch_bounds__(256) void stage_mfma4(
    const u16* __restrict__ yin, const u16* __restrict__ bpre,
    const int* __restrict__ m_in_i, const u8* __restrict__ m_in_u8,
    u16* __restrict__ yout, u8* __restrict__ m_out,
    float* __restrict__ pool_sum, float* __restrict__ cnt,
    const int stage)
{
  __shared__ u16 lb[14 * 512];
  __shared__ float lmp[256];
  __shared__ float lps[4][16];

  constexpr int So = S >> 1;
  constexpr int nvox = So * So * So;
  constexpr int NBX = nvox / 256;
  const int b = blockIdx.y;
  const int tid = threadIdx.x;
  const int u = blockIdx.x;
  int bxi;
  if constexpr (NBX >= 8) bxi = (u & 7) * (NBX / 8) + (u >> 3);
  else bxi = u;
  const int vg0 = bxi * 256;

  {
    const uint4* src = (const uint4*)bpre;
    uint4* dst = (uint4*)lb;
    for (int e = tid; e < 896; e += 256) dst[e] = src[e];
  }

  {
    const int vox = vg0 + tid;
    const int oz = vox / (So * So);
    const int oy = (vox / So) % So;
    const int ox = vox % So;
    float mp = 0.f;
    if (m_in_i) {
      // x-pairs are contiguous + 8B aligned: int2 loads (4 instead of 8)
#pragma unroll
      for (int dz = 0; dz < 2; ++dz)
#pragma unroll
        for (int dy = 0; dy < 2; ++dy) {
          const int2 v = *(const int2*)(m_in_i +
              ((b * S + 2 * oz + dz) * S + 2 * oy + dy) * S + 2 * ox);
          mp = fmaxf(mp, (float)max(v.x, v.y));
        }
    } else {
#pragma unroll
      for (int dz = 0; dz < 2; ++dz)
#pragma unroll
        for (int dy = 0; dy < 2; ++dy)
#pragma unroll
          for (int dx = 0; dx < 2; ++dx) {
            const int mi =
                ((b * S + 2 * oz + dz) * S + 2 * oy + dy) * S + 2 * ox + dx;
            mp = fmaxf(mp, (float)m_in_u8[mi]);
          }
    }
    lmp[tid] = mp;
  }
  __syncthreads();

  const int wv = tid >> 6;
  const int lane = tid & 63;
  const int m = lane & 15;
  const int quad = lane >> 4;
  const int qh = quad >> 1;
  const int qlo = quad & 1;

  int izb[4], iyb[4], ixb[4];
#pragma unroll
  for (int g = 0; g < 4; ++g) {
    const int vox = vg0 + wv * 64 + g * 16 + m;
    const int oz = vox / (So * So);
    const int oy = (vox / So) % So;
    const int ox = vox % So;
    izb[g] = 2 * oz - 1;
    iyb[g] = 2 * oy - 1;
    ixb[g] = 2 * ox - 1;
  }

  const s16x8* lbv = (const s16x8*)lb;
  f32x4 acc[4];
#pragma unroll
  for (int g = 0; g < 4; ++g) acc[g] = (f32x4){0.f, 0.f, 0.f, 0.f};

#pragma unroll
  for (int i = 0; i < 14; ++i) {
    const int t0 = 2 * i, t1 = 2 * i + 1;
    const int dz0 = t0 / 9, dy0 = (t0 / 3) % 3, dx0 = t0 % 3;
    const int dz1 = (t1 < 27) ? t1 / 9 : 1;
    const int dy1 = (t1 < 27) ? (t1 / 3) % 3 : 1;
    const int dx1 = (t1 < 27) ? t1 % 3 : 1;
    const int dzq = qh ? dz1 : dz0;
    const int dyq = qh ? dy1 : dy0;
    const int dxq = qh ? dx1 : dx0;

    uint4 ar[4];
#pragma unroll
    for (int g = 0; g < 4; ++g) {
      const int iz = izb[g] + dzq;
      const int iy = iyb[g] + dyq;
      const int ix = ixb[g] + dxq;
      const bool valid = (unsigned)iz < (unsigned)S &&
                         (unsigned)iy < (unsigned)S &&
                         (unsigned)ix < (unsigned)S;
      const int izc = min(max(iz, 0), S - 1);
      const int iyc = min(max(iy, 0), S - 1);
      const int ixc = min(max(ix, 0), S - 1);
      const size_t addr =
          (size_t)(((b * S + izc) * S + iyc) * S + ixc) * 16 + qlo * 8;
      uint4 v = *(const uint4*)(yin + addr);
      v.x = valid ? v.x : 0u;
      v.y = valid ? v.y : 0u;
      v.z = valid ? v.z : 0u;
      v.w = valid ? v.w : 0u;
      ar[g] = v;
    }
    const s16x8 bfrag = lbv[i * 64 + lane];
#pragma unroll
    for (int g = 0; g < 4; ++g)
      acc[g] = __builtin_amdgcn_mfma_f32_16x16x32_bf16(
          bfrag, __builtin_bit_cast(s16x8, ar[g]), acc[g], 0, 0, 0);
  }

  {
    float ps0 = 0.f, ps1 = 0.f, ps2 = 0.f, ps3 = 0.f;
#pragma unroll
    for (int g = 0; g < 4; ++g) {
      const int lv = wv * 64 + g * 16 + m;
      const float mp = lmp[lv];
      const float f0 = fmaxf(acc[g][0], 0.f) * mp;
      const float f1 = fmaxf(acc[g][1], 0.f) * mp;
      const float f2 = fmaxf(acc[g][2], 0.f) * mp;
      const float f3 = fmaxf(acc[g][3], 0.f) * mp;
      const size_t gi = (size_t)b * nvox + vg0 + lv;
      *(uint2*)(yout + gi * 16 + quad * 4) =
          make_uint2(packbf_hw(f0, f1), packbf_hw(f2, f3));
      if (quad == 0) m_out[gi] = (u8)mp;
      ps0 += f0; ps1 += f1; ps2 += f2; ps3 += f3;
    }
#pragma unroll
    for (int mm = 1; mm < 16; mm <<= 1) {
      ps0 += __shfl_xor(ps0, mm, 64);
      ps1 += __shfl_xor(ps1, mm, 64);
      ps2 += __shfl_xor(ps2, mm, 64);
      ps3 += __shfl_xor(ps3, mm, 64);
    }
    if (m == 0) {
      lps[wv][quad * 4 + 0] = ps0;
      lps[wv][quad * 4 + 1] = ps1;
      lps[wv][quad * 4 + 2] = ps2;
      lps[wv][quad * 4 + 3] = ps3;
    }
  }
  __syncthreads();
  if (tid < 16) {
    const float s = lps[0][tid] + lps[1][tid] + lps[2][tid] + lps[3][tid];
    atomicAdd(&pool_sum[(b * 6 + stage) * 16 + tid], s);
  } else if (tid == 16) {
    float c = 0.f;
#pragma unroll 16
    for (int v = 0; v < 256; ++v) c += lmp[v];
    atomicAdd(&cnt[b * 6 + stage], c);
  }
}

// --------- Tail: stage 2 fused (swapped-operand MFMA, y3 kept in LDS) +
// stage 3 MFMA (K split over 4 waves) + stages 4/5 split-K VALU + MLP head.
// One block per batch; reads y2/m2 directly (L2-hot). ----------------------
__global__ __launch_bounds__(256) void tail_kernel(
    const u16* __restrict__ y2g, const u8* __restrict__ m2g,
    const u16* __restrict__ bpre,
    const float* __restrict__ wstg,
    const float* __restrict__ meta, const float* __restrict__ sched,
    const float* __restrict__ mw1, const float* __restrict__ mb1,
    const float* __restrict__ mw2, const float* __restrict__ mb2,
    const float* __restrict__ matw, const float* __restrict__ matb,
    const float* __restrict__ schw, const float* __restrict__ schb,
    const float* __restrict__ f1w, const float* __restrict__ f1b,
    const float* __restrict__ f2w, const float* __restrict__ f2b,
    const float* __restrict__ pool_sum, const float* __restrict__ cnt,
    float* __restrict__ out)
{
  const int b = blockIdx.x;
  const int t = threadIdx.x;
  __shared__ u16 ty3[8192];           // y3 in bf16 (built in-LDS by stage 2)
  __shared__ float lm3[512];
  __shared__ float pb[4 * 64 * 17];   // stage-3 wave partials (pad 17)
  __shared__ float ly4[64 * 16];
  __shared__ float lm4[64];
  __shared__ float ps4[256];
  __shared__ float ly5[8 * 16];
  __shared__ float lm5[8];
  __shared__ float ps5[128];
  __shared__ float lsum[4][16];       // stage 2,3,4,5 pool sums
  __shared__ float lcnt[4];
  __shared__ float lps2[4][16];
  __shared__ float lcw[4];
  __shared__ float invec[112];
  __shared__ float hbuf[32];
  __shared__ float zbuf[256];
  __shared__ float psf[256];
  __shared__ float part[2];

  const int lane = t & 63;
  const int wv = t >> 6;
  const int mm = lane & 15;
  const int quad = lane >> 4;
  const int qh = quad >> 1, qlo = quad & 1;

  // ---- P0: stage 2 (16->8), swapped operands, output straight into LDS ----
  {
    const s16x8* bp2 = (const s16x8*)(bpre + 2 * 7168);
    float ps0 = 0.f, ps1 = 0.f, ps2 = 0.f, ps3 = 0.f;
    float cmask = 0.f;
#pragma unroll
    for (int p = 0; p < 2; ++p) {
      const int vg0 = p * 256;
      {
        const int vox = vg0 + t;
        const int oz = vox >> 6, oy = (vox >> 3) & 7, ox = vox & 7;
        float mp = 0.f;
#pragma unroll
        for (int dz = 0; dz < 2; ++dz)
#pragma unroll
          for (int dy = 0; dy < 2; ++dy)
#pragma unroll
            for (int dx = 0; dx < 2; ++dx)
              mp = fmaxf(mp, (float)m2g[((b * 16 + 2 * oz + dz) * 16 +
                                         2 * oy + dy) * 16 + 2 * ox + dx]);
        lm3[vox] = mp;
        cmask += mp;
      }
      int izb[4], iyb[4], ixb[4];
#pragma unroll
      for (int g = 0; g < 4; ++g) {
        const int vox = vg0 + wv * 64 + g * 16 + mm;
        izb[g] = 2 * (vox >> 6) - 1;
        iyb[g] = 2 * ((vox >> 3) & 7) - 1;
        ixb[g] = 2 * (vox & 7) - 1;
      }
      f32x4 acc[4];
#pragma unroll
      for (int g = 0; g < 4; ++g) acc[g] = (f32x4){0.f, 0.f, 0.f, 0.f};
#pragma unroll
      for (int i = 0; i < 14; ++i) {
        const int t0 = 2 * i, t1 = 2 * i + 1;
        const int dz0 = t0 / 9, dy0 = (t0 / 3) % 3, dx0 = t0 % 3;
        const int dz1 = (t1 < 27) ? t1 / 9 : 1;
        const int dy1 = (t1 < 27) ? (t1 / 3) % 3 : 1;
        const int dx1 = (t1 < 27) ? t1 % 3 : 1;
        const int dzq = qh ? dz1 : dz0;
        const int dyq = qh ? dy1 : dy0;
        const int dxq = qh ? dx1 : dx0;
        uint4 ar[4];
#pragma unroll
        for (int g = 0; g < 4; ++g) {
          const int iz = izb[g] + dzq;
          const int iy = iyb[g] + dyq;
          const int ix = ixb[g] + dxq;
          const bool valid = (unsigned)iz < 16u && (unsigned)iy < 16u &&
                             (unsigned)ix < 16u;
          const int izc = min(max(iz, 0), 15);
          const int iyc = min(max(iy, 0), 15);
          const int ixc = min(max(ix, 0), 15);
          const size_t addr =
              (size_t)(((b * 16 + izc) * 16 + iyc) * 16 + ixc) * 16 + qlo * 8;
          uint4 v = *(const uint4*)(y2g + addr);
          v.x = valid ? v.x : 0u;
          v.y = valid ? v.y : 0u;
          v.z = valid ? v.z : 0u;
          v.w = valid ? v.w : 0u;
          ar[g] = v;
        }
        const s16x8 bfrag = bp2[i * 64 + lane];
#pragma unroll
        for (int g = 0; g < 4; ++g)
          acc[g] = __builtin_amdgcn_mfma_f32_16x16x32_bf16(
              bfrag, __builtin_bit_cast(s16x8, ar[g]), acc[g], 0, 0, 0);
      }
      __syncthreads();                 // lm3 of this pass visible
#pragma unroll
      for (int g = 0; g < 4; ++g) {
        const int lv = vg0 + wv * 64 + g * 16 + mm;
        const float mp = lm3[lv];
        const float f0 = fmaxf(acc[g][0], 0.f) * mp;
        const float f1 = fmaxf(acc[g][1], 0.f) * mp;
        const float f2 = fmaxf(acc[g][2], 0.f) * mp;
        const float f3 = fmaxf(acc[g][3], 0.f) * mp;
        *(uint2*)&ty3[lv * 16 + quad * 4] =
            make_uint2(packbf_hw(f0, f1), packbf_hw(f2, f3));
        ps0 += f0; ps1 += f1; ps2 += f2; ps3 += f3;
      }
    }
    // channel pool sums over both passes
#pragma unroll
    for (int s = 1; s < 16; s <<= 1) {
      ps0 += __shfl_xor(ps0, s, 64);
      ps1 += __shfl_xor(ps1, s, 64);
      ps2 += __shfl_xor(ps2, s, 64);
      ps3 += __shfl_xor(ps3, s, 64);
    }
    if (mm == 0) {
      lps2[wv][quad * 4 + 0] = ps0;
      lps2[wv][quad * 4 + 1] = ps1;
      lps2[wv][quad * 4 + 2] = ps2;
      lps2[wv][quad * 4 + 3] = ps3;
    }
    // mask count (each thread owns lm3[t] and lm3[256+t])
#pragma unroll
    for (int s = 1; s < 64; s <<= 1) cmask += __shfl_xor(cmask, s, 64);
    if (lane == 0) lcw[wv] = cmask;
  }
  __syncthreads();
  if (t < 16) {
    lsum[0][t] = lps2[0][t] + lps2[1][t] + lps2[2][t] + lps2[3][t];
  } else if (t == 16) {
    lcnt[0] = lcw[0] + lcw[1] + lcw[2] + lcw[3];
  }

  // ---- P1: stage 3 MFMA, tap-pairs split across waves (reads ty3/LDS) ----
  {
    int iz0[4], iy0[4], ix0[4];
#pragma unroll
    for (int g = 0; g < 4; ++g) {
      const int vox = g * 16 + mm;
      iz0[g] = 2 * (vox >> 4) - 1;
      iy0[g] = 2 * ((vox >> 2) & 3) - 1;
      ix0[g] = 2 * (vox & 3) - 1;
    }
    f32x4 a3[4];
#pragma unroll
    for (int g = 0; g < 4; ++g) a3[g] = (f32x4){0.f, 0.f, 0.f, 0.f};
    const s16x8* bp3 = (const s16x8*)(bpre + 3 * 7168);
#pragma unroll
    for (int ii = 0; ii < 4; ++ii) {
      const int i = wv * 4 + ii;
      if (i < 14) {
        const int t0 = 2 * i, t1 = 2 * i + 1;
        const int dz0 = t0 / 9, dy0 = (t0 / 3) % 3, dx0 = t0 % 3;
        const int dz1 = (t1 < 27) ? t1 / 9 : 1;
        const int dy1 = (t1 < 27) ? (t1 / 3) % 3 : 1;
        const int dx1 = (t1 < 27) ? t1 % 3 : 1;
        const int dzq = qh ? dz1 : dz0;
        const int dyq = qh ? dy1 : dy0;
        const int dxq = qh ? dx1 : dx0;
        uint4 ar[4];
#pragma unroll
        for (int g = 0; g < 4; ++g) {
          const int iz = iz0[g] + dzq;
          const int iy = iy0[g] + dyq;
          const int ix = ix0[g] + dxq;
          const bool valid = (unsigned)iz < 8u && (unsigned)iy < 8u &&
                             (unsigned)ix < 8u;
          const int izc = min(max(iz, 0), 7);
          const int iyc = min(max(iy, 0), 7);
          const int ixc = min(max(ix, 0), 7);
          const int ad = ((izc * 8 + iyc) * 8 + ixc) * 16 + qlo * 8;
          uint4 v = *(const uint4*)&ty3[ad];
          v.x = valid ? v.x : 0u;
          v.y = valid ? v.y : 0u;
          v.z = valid ? v.z : 0u;
          v.w = valid ? v.w : 0u;
          ar[g] = v;
        }
        const s16x8 bf = bp3[i * 64 + lane];
#pragma unroll
        for (int g = 0; g < 4; ++g)
          a3[g] = __builtin_amdgcn_mfma_f32_16x16x32_bf16(
              __builtin_bit_cast(s16x8, ar[g]), bf, a3[g], 0, 0, 0);
      }
    }
#pragma unroll
    for (int g = 0; g < 4; ++g)
#pragma unroll
      for (int reg = 0; reg < 4; ++reg)
        pb[wv * 1088 + (g * 16 + quad * 4 + reg) * 17 + mm] = a3[g][reg];
  }
  __syncthreads();

  // ---- P2: reduce 4 wave-partials -> relu * mask -> ly4 (f32)
  {
    const int vox = t >> 2, cg = (t & 3) * 4;
    const int oz = vox >> 4, oy = (vox >> 2) & 3, ox = vox & 3;
    float mp = 0.f;
#pragma unroll
    for (int dz = 0; dz < 2; ++dz)
#pragma unroll
      for (int dy = 0; dy < 2; ++dy)
#pragma unroll
        for (int dx = 0; dx < 2; ++dx)
          mp = fmaxf(mp, lm3[((2 * oz + dz) * 8 + 2 * oy + dy) * 8 +
                             2 * ox + dx]);
#pragma unroll
    for (int c = 0; c < 4; ++c) {
      const int ch = cg + c;
      const float s = pb[vox * 17 + ch] + pb[1088 + vox * 17 + ch] +
                      pb[2176 + vox * 17 + ch] + pb[3264 + vox * 17 + ch];
      ly4[vox * 16 + ch] = fmaxf(s, 0.f) * mp;
    }
    if (cg == 0) lm4[vox] = mp;
  }
  __syncthreads();

  // ---- P3: stage-3 pools + stage 4 split-K (all 256 threads)
  if (t < 16) {
    float s = 0.f;
#pragma unroll 16
    for (int v = 0; v < 64; ++v) s += ly4[v * 16 + t];
    lsum[1][t] = s;
  } else if (t == 16) {
    float s = 0.f;
#pragma unroll 16
    for (int v = 0; v < 64; ++v) s += lm4[v];
    lcnt[1] = s;
  }
  {
    const float* w = wstg + 4 * 27 * 256;
    const int o = t >> 1, kh = t & 1;
    const int vox4 = o >> 4, co = o & 15;
    const int oz = vox4 >> 2, oy = (vox4 >> 1) & 1, ox = vox4 & 1;
    float acc = 0.f;
#pragma unroll
    for (int tt = 0; tt < 14; ++tt) {
      const int tap = tt + (kh ? 14 : 0);
      if (tap < 27) {
        const int dz = tap / 9, dy = (tap / 3) % 3, dx = tap % 3;
        const int iz = 2 * oz + dz - 1, iy = 2 * oy + dy - 1,
                  ix = 2 * ox + dx - 1;
        const float s = ((unsigned)iz < 4u && (unsigned)iy < 4u &&
                         (unsigned)ix < 4u) ? 1.f : 0.f;
        const int idx = ((min(max(iz, 0), 3) * 4 + min(max(iy, 0), 3)) * 4 +
                         min(max(ix, 0), 3)) * 16;
        const float* wp = w + tap * 256 + co;
#pragma unroll
        for (int ci = 0; ci < 16; ++ci)
          acc = fmaf(ly4[idx + ci] * s, wp[ci * 16], acc);
      }
    }
    ps4[t] = acc;
  }
  __syncthreads();

  // ---- P4: combine stage-4 partials -> ly5
  if (t < 128) {
    const int vox4 = t >> 4, co = t & 15;
    float mp = 0.f;
#pragma unroll
    for (int dz = 0; dz < 2; ++dz)
#pragma unroll
      for (int dy = 0; dy < 2; ++dy)
#pragma unroll
        for (int dx = 0; dx < 2; ++dx)
          mp = fmaxf(mp, lm4[((2 * (vox4 >> 2) + dz) * 4 +
                              2 * ((vox4 >> 1) & 1) + dy) * 4 +
                             2 * (vox4 & 1) + dx]);
    ly5[t] = fmaxf(ps4[2 * t] + ps4[2 * t + 1], 0.f) * mp;
    if (co == 0) lm5[vox4] = mp;
  }
  __syncthreads();

  // ---- P5: stage-4 pools + stage 5 split-K (128 threads, 8 K-slices)
  if (t < 16) {
    float s = 0.f;
#pragma unroll
    for (int v = 0; v < 8; ++v) s += ly5[v * 16 + t];
    lsum[2][t] = s;
  } else if (t == 16) {
    lcnt[2] = lm5[0] + lm5[1] + lm5[2] + lm5[3] + lm5[4] + lm5[5] + lm5[6] +
              lm5[7];
  }
  if (t < 128) {
    const float* w = wstg + 5 * 27 * 256;
    const int co = t & 15, k8 = t >> 4;
    float acc = 0.f;
#pragma unroll
    for (int tt = 0; tt < 4; ++tt) {
      const int tap = k8 * 4 + tt;
      if (tap < 27) {
        const int dz = tap / 9, dy = (tap / 3) % 3, dx = tap % 3;
        const int iz = dz - 1, iy = dy - 1, ix = dx - 1;
        const float s = ((unsigned)iz < 2u && (unsigned)iy < 2u &&
                         (unsigned)ix < 2u) ? 1.f : 0.f;
        const int idx = ((min(max(iz, 0), 1) * 2 + min(max(iy, 0), 1)) * 2 +
                         min(max(ix, 0), 1)) * 16;
        const float* wp = w + tap * 256 + co;
#pragma unroll
        for (int ci = 0; ci < 16; ++ci)
          acc = fmaf(ly5[idx + ci] * s, wp[ci * 16], acc);
      }
    }
    ps5[t] = acc;
  }
  __syncthreads();

  // ---- P6: combine stage-5 partials; meta layer 1
  if (t < 16) {
    float s = ps5[t] + ps5[16 + t] + ps5[32 + t] + ps5[48 + t] +
              ps5[64 + t] + ps5[80 + t] + ps5[96 + t] + ps5[112 + t];
    float mp = 0.f;
#pragma unroll
    for (int v = 0; v < 8; ++v) mp = fmaxf(mp, lm5[v]);
    lsum[3][t] = fmaxf(s, 0.f) * mp;
    if (t == 0) lcnt[3] = mp;
  } else if (t >= 96 && t < 128) {
    const int j = t - 96;
    float h = mb1[j];
#pragma unroll
    for (int k = 0; k < 3; ++k) h = fmaf(meta[b * 3 + k], mw1[k * 32 + j], h);
    hbuf[j] = fmaxf(h, 0.f);
  }
  __syncthreads();

  // ---- P7: build invec (stages 0,1 from global; 2..5 local; meta_emb)
  if (t < 32) {
    const int s = t >> 4;
    invec[t] = pool_sum[b * 96 + t] / fmaxf(cnt[b * 6 + s], 1.f);
  } else if (t < 96) {
    const int s = (t >> 4) - 2;
    invec[t] = lsum[s][t & 15] / fmaxf(lcnt[s], 1.f);
  } else if (t < 112) {
    const int j = t - 96;
    float e = mb2[j];
#pragma unroll
    for (int k = 0; k < 32; ++k) e = fmaf(hbuf[k], mw2[k * 16 + j], e);
    invec[t] = e;  // no ReLU on meta_emb
  }
  __syncthreads();

  // ---- P8: zbuf = [relu(invec@matw), relu(sched@schw)] in parallel halves
  if (t < 128) {
    float a = matb[t];
#pragma unroll 16
    for (int k = 0; k < 112; ++k) a = fmaf(invec[k], matw[k * 128 + t], a);
    zbuf[t] = fmaxf(a, 0.f);
  } else {
    const int c = t - 128;
    float s = schb[c];
#pragma unroll 16
    for (int k = 0; k < 128; ++k)
      s = fmaf(sched[b * 128 + k], schw[k * 128 + c], s);
    zbuf[128 + c] = fmaxf(s, 0.f);
  }
  __syncthreads();

  // ---- P9: f1 with K split across thread halves
  {
    const int col = t & 127, kh = t >> 7;
    float a = 0.f;
#pragma unroll 16
    for (int kk = 0; kk < 128; ++kk) {
      const int k = kh * 128 + kk;
      a = fmaf(zbuf[k], f1w[k * 128 + col], a);
    }
    psf[t] = a;
  }
  __syncthreads();

  // ---- P10: final combine + dot with f2w
  if (t < 128) {
    const float a = psf[t] + psf[128 + t] + f1b[t];
    float v = fmaxf(a, 0.f) * f2w[t];
#pragma unroll
    for (int off = 32; off > 0; off >>= 1) v += __shfl_xor(v, off, 64);
    if ((t & 63) == 0) part[t >> 6] = v;
  }
  __syncthreads();
  if (t == 0) out[b] = part[0] + part[1] + f2b[0];
}

extern "C" void kernel_launch(void* const* d_in, const int* in_sizes, int n_in,
                              void* d_out, int out_size, void* d_ws,
                              size_t ws_size, hipStream_t stream)
{
  (void)in_sizes; (void)n_in; (void)out_size; (void)ws_size;
  const float* x      = (const float*)d_in[0];
  const int*   mask   = (const int*)  d_in[1];
  const float* meta   = (const float*)d_in[2];
  const float* sched  = (const float*)d_in[3];
  const float* w_stem = (const float*)d_in[4];
  const float* w_stg  = (const float*)d_in[5];
  const float* mw1    = (const float*)d_in[6];
  const float* mb1    = (const float*)d_in[7];
  const float* mw2    = (const float*)d_in[8];
  const float* mb2    = (const float*)d_in[9];
  const float* matw   = (const float*)d_in[10];
  const float* matb   = (const float*)d_in[11];
  const float* schw   = (const float*)d_in[12];
  const float* schb   = (const float*)d_in[13];
  const float* f1w    = (const float*)d_in[14];
  const float* f1b    = (const float*)d_in[15];
  const float* f2w    = (const float*)d_in[16];
  const float* f2b    = (const float*)d_in[17];
  float* out = (float*)d_out;

  char* ws = (char*)d_ws;
  size_t off = 0;
  auto alloc = [&](size_t nbytes) -> void* {
    void* p = ws + off;
    off += (nbytes + 255) & ~(size_t)255;
    return p;
  };

  u16* y0 = (u16*)alloc((size_t)NB * 64 * 64 * 64 * CH * 2);
  u16* y1 = (u16*)alloc((size_t)NB * 32 * 32 * 32 * CH * 2);
  u16* y2 = (u16*)alloc((size_t)NB * 16 * 16 * 16 * CH * 2);
  u8* m1 = (u8*)alloc((size_t)NB * 32 * 32 * 32);
  u8* m2 = (u8*)alloc((size_t)NB * 16 * 16 * 16);
  float* pool_sum = (float*)alloc((NB * 96 + NB * 6) * 4);
  float* cnt = pool_sum + NB * 96;
  u16* bpre = (u16*)alloc((4 * 7168 + 3584) * 2);

  bprep_kernel<<<126, 256, 0, stream>>>(w_stg, w_stem, bpre);

  stem_mfma<<<dim3(512, NB), 256, 0, stream>>>(x, mask, bpre, y0,
                                               pool_sum, cnt);

  // stage 0: 64->32 (32768 vox / 256 = 128 blocks/batch)
  stage_mfma4<64><<<dim3(128, NB), 256, 0, stream>>>(
      y0, bpre + 0 * 7168, mask, (const u8*)nullptr, y1, m1,
      pool_sum, cnt, 0);
  // stage 1: 32->16 (16 blocks/batch)
  stage_mfma4<32><<<dim3(16, NB), 256, 0, stream>>>(
      y1, bpre + 1 * 7168, (const int*)nullptr, m1, y2, m2,
      pool_sum, cnt, 1);

  // stage 2 fused into tail (reads y2/m2 directly, y3 lives in LDS)
  tail_kernel<<<NB, 256, 0, stream>>>(y2, m2, bpre, w_stg, meta, sched,
                                      mw1, mb1, mw2, mb2, matw, matb,
                                      schw, schb, f1w, f1b, f2w, f2b,
                                      pool_sum, cnt, out);
}